// Round 1
// baseline (549.010 us; speedup 1.0000x reference)
//
#include <hip/hip_runtime.h>
#include <hip/hip_bf16.h>
#include <math.h>

#define N_TOK 1024
#define N_ATOM 24576
#define C_S 384
#define FDIM 256
#define NH 4
#define HD 96

// ---- workspace layout (float offsets, all 16B-aligned) ----
#define OFF_SEGX   0u          // 1024*4  (sum x,y,z,count)
#define OFF_NOISE  4096u       // 256
#define OFF_NSPROJ 4352u       // 384
#define OFF_TF1    4736u       // 1024*384
#define OFF_QKV    397952u     // 1024*1152
#define OFF_AO     1577600u    // 1024*384
#define OFF_TF2    1970816u    // 1024*384
#define OFF_LNH    2364032u    // 1024*384
#define OFF_H1     2757248u    // 1024*1536
#define OFF_TF3    4330112u    // 1024*384
#define OFF_TOUT   4723328u    // 1024*3

// ---------------------------------------------------------------------------
// small setup: fourier embedding -> noise [256] -> ns_proj [384]
__global__ __launch_bounds__(384) void k_setup(
    const float* __restrict__ sigma,
    const float* __restrict__ fw, const float* __restrict__ fb,
    const float* __restrict__ nsw, const float* __restrict__ nsb,
    float* __restrict__ noise_out, float* __restrict__ nsproj_out)
{
    __shared__ float emb[256];
    __shared__ float noise[256];
    int tid = threadIdx.x;
    float sg = sigma[0];
    if (tid < 128) {
        float fr = expf(-logf(1000.f) * (float)tid / 128.f);
        float x = sg * fr;
        emb[tid]       = cosf(x);
        emb[tid + 128] = sinf(x);
    }
    __syncthreads();
    if (tid < 256) {
        const float* wr = fw + (size_t)tid * 256;
        float acc = fb[tid];
        for (int i = 0; i < 256; i++) acc += emb[i] * wr[i];
        noise[tid] = acc;
        noise_out[tid] = acc;
    }
    __syncthreads();
    if (tid < 384) {
        const float* wr = nsw + (size_t)tid * 256;
        float acc = nsb[tid];
        for (int i = 0; i < 256; i++) acc += noise[i] * wr[i];
        nsproj_out[tid] = acc;
    }
}

// ---------------------------------------------------------------------------
// segment sum of raw coords + counts (project AFTER the mean: 100x less work)
__global__ __launch_bounds__(256) void k_segsum(
    const float* __restrict__ x, const int* __restrict__ idx,
    float* __restrict__ segx)
{
    int a = blockIdx.x * 256 + threadIdx.x;
    if (a < N_ATOM) {
        int t = idx[a];
        atomicAdd(&segx[t * 4 + 0], x[a * 3 + 0]);
        atomicAdd(&segx[t * 4 + 1], x[a * 3 + 1]);
        atomicAdd(&segx[t * 4 + 2], x[a * 3 + 2]);
        atomicAdd(&segx[t * 4 + 3], 1.f);
    }
}

// ---------------------------------------------------------------------------
__device__ inline float blockReduceSum128(float v, volatile float* sm)
{
    #pragma unroll
    for (int off = 32; off > 0; off >>= 1) v += __shfl_down(v, off);
    if ((threadIdx.x & 63) == 0) sm[threadIdx.x >> 6] = v;
    __syncthreads();
    float r = sm[0] + sm[1];
    __syncthreads();
    return r;
}

// token_feat = LN(s)*g+b + ns_proj + (cnt>0 ? mean_x@ce_w.T + ce_b : 0)
__global__ __launch_bounds__(128) void k_tokenfeat(
    const float* __restrict__ s, const float* __restrict__ segx,
    const float* __restrict__ nsproj,
    const float* __restrict__ g, const float* __restrict__ b,
    const float* __restrict__ ce_w, const float* __restrict__ ce_b,
    float* __restrict__ tf)
{
    __shared__ float sm[2];
    int t = blockIdx.x, tid = threadIdx.x;
    const float* sr = s + (size_t)t * C_S;
    float x0 = sr[tid], x1 = sr[tid + 128], x2 = sr[tid + 256];
    float total = blockReduceSum128(x0 + x1 + x2, sm);
    float mean = total * (1.f / 384.f);
    float d0 = x0 - mean, d1 = x1 - mean, d2 = x2 - mean;
    float vtot = blockReduceSum128(d0 * d0 + d1 * d1 + d2 * d2, sm);
    float inv = rsqrtf(vtot * (1.f / 384.f) + 1e-5f);
    float cnt = segx[t * 4 + 3];
    float mx0 = 0.f, mx1 = 0.f, mx2 = 0.f;
    int has = cnt > 0.f;
    if (has) {
        float ic = 1.f / cnt;
        mx0 = segx[t * 4 + 0] * ic;
        mx1 = segx[t * 4 + 1] * ic;
        mx2 = segx[t * 4 + 2] * ic;
    }
    float xs[3] = {d0, d1, d2};
    #pragma unroll
    for (int l = 0; l < 3; l++) {
        int c = tid + l * 128;
        float ln = xs[l] * inv * g[c] + b[c];
        float coord = 0.f;
        if (has)
            coord = mx0 * ce_w[c * 3 + 0] + mx1 * ce_w[c * 3 + 1]
                  + mx2 * ce_w[c * 3 + 2] + ce_b[c];
        tf[(size_t)t * C_S + c] = ln + nsproj[c] + coord;
    }
}

// plain LN (for ffln)
__global__ __launch_bounds__(128) void k_ln(
    const float* __restrict__ in, const float* __restrict__ g,
    const float* __restrict__ b, float* __restrict__ out)
{
    __shared__ float sm[2];
    int t = blockIdx.x, tid = threadIdx.x;
    const float* sr = in + (size_t)t * C_S;
    float x0 = sr[tid], x1 = sr[tid + 128], x2 = sr[tid + 256];
    float total = blockReduceSum128(x0 + x1 + x2, sm);
    float mean = total * (1.f / 384.f);
    float d0 = x0 - mean, d1 = x1 - mean, d2 = x2 - mean;
    float vtot = blockReduceSum128(d0 * d0 + d1 * d1 + d2 * d2, sm);
    float inv = rsqrtf(vtot * (1.f / 384.f) + 1e-5f);
    float xs[3] = {d0, d1, d2};
    #pragma unroll
    for (int l = 0; l < 3; l++) {
        int c = tid + l * 128;
        out[(size_t)t * C_S + c] = xs[l] * inv * g[c] + b[c];
    }
}

// ---------------------------------------------------------------------------
// C[M,N] = act(A[M,K] @ W[N,K]^T + bias) (+ res). 64x64 tile, BK=16, 4x4/thread.
template <int ACT, bool RES>
__global__ __launch_bounds__(256) void k_gemm(
    const float* __restrict__ A, const float* __restrict__ W,
    const float* __restrict__ bias, const float* __restrict__ res,
    float* __restrict__ C, int M, int N, int K)
{
    __shared__ float As[16][65];
    __shared__ float Bs[16][65];
    int bm = blockIdx.y * 64;
    int bn = blockIdx.x * 64;
    int tid = threadIdx.x;
    int tx = tid & 15, ty = tid >> 4;
    int li = tid >> 2;           // 0..63
    int lj = (tid & 3) << 2;     // 0,4,8,12
    float acc[4][4] = {};
    for (int k0 = 0; k0 < K; k0 += 16) {
        float4 av = *(const float4*)(A + (size_t)(bm + li) * K + k0 + lj);
        float4 bv = *(const float4*)(W + (size_t)(bn + li) * K + k0 + lj);
        As[lj + 0][li] = av.x; As[lj + 1][li] = av.y;
        As[lj + 2][li] = av.z; As[lj + 3][li] = av.w;
        Bs[lj + 0][li] = bv.x; Bs[lj + 1][li] = bv.y;
        Bs[lj + 2][li] = bv.z; Bs[lj + 3][li] = bv.w;
        __syncthreads();
        #pragma unroll
        for (int k = 0; k < 16; k++) {
            float a[4], b[4];
            #pragma unroll
            for (int ii = 0; ii < 4; ii++) a[ii] = As[k][ty + 16 * ii];
            #pragma unroll
            for (int jj = 0; jj < 4; jj++) b[jj] = Bs[k][tx + 16 * jj];
            #pragma unroll
            for (int ii = 0; ii < 4; ii++)
                #pragma unroll
                for (int jj = 0; jj < 4; jj++)
                    acc[ii][jj] += a[ii] * b[jj];
        }
        __syncthreads();
    }
    #pragma unroll
    for (int ii = 0; ii < 4; ii++) {
        int m = bm + ty + 16 * ii;
        #pragma unroll
        for (int jj = 0; jj < 4; jj++) {
            int n = bn + tx + 16 * jj;
            float v = acc[ii][jj] + bias[n];
            if (ACT == 1) v = v / (1.f + expf(-v));   // silu
            if (RES) v += res[(size_t)m * N + n];
            C[(size_t)m * N + n] = v;
        }
    }
}

// ---------------------------------------------------------------------------
// per-(row,head) attention: scores -> softmax -> PV, no materialized S matrix
__global__ __launch_bounds__(256) void k_attn(
    const float* __restrict__ qkv, float* __restrict__ ao)
{
    __shared__ float qs[HD];
    __shared__ float ps[N_TOK];
    __shared__ float red[4];
    __shared__ float pv[2][HD];
    int row = blockIdx.x, h = blockIdx.y, tid = threadIdx.x;
    const float scale = rsqrtf((float)HD);
    for (int d = tid; d < HD; d += 256)
        qs[d] = qkv[(size_t)row * 1152 + h * HD + d];
    __syncthreads();
    // scores + local max
    float lmax = -1e30f;
    for (int t = tid; t < N_TOK; t += 256) {
        const float4* kr4 = (const float4*)(qkv + (size_t)t * 1152 + 384 + h * HD);
        float sum = 0.f;
        #pragma unroll
        for (int d4 = 0; d4 < HD / 4; d4++) {
            float4 kv = kr4[d4];
            sum += qs[d4 * 4 + 0] * kv.x + qs[d4 * 4 + 1] * kv.y
                 + qs[d4 * 4 + 2] * kv.z + qs[d4 * 4 + 3] * kv.w;
        }
        sum *= scale;
        ps[t] = sum;
        lmax = fmaxf(lmax, sum);
    }
    #pragma unroll
    for (int off = 32; off > 0; off >>= 1) lmax = fmaxf(lmax, __shfl_down(lmax, off));
    if ((tid & 63) == 0) red[tid >> 6] = lmax;
    __syncthreads();
    float m = fmaxf(fmaxf(red[0], red[1]), fmaxf(red[2], red[3]));
    __syncthreads();
    // exp + sum
    float lsum = 0.f;
    for (int t = tid; t < N_TOK; t += 256) {
        float p = __expf(ps[t] - m);
        ps[t] = p;
        lsum += p;
    }
    #pragma unroll
    for (int off = 32; off > 0; off >>= 1) lsum += __shfl_down(lsum, off);
    if ((tid & 63) == 0) red[tid >> 6] = lsum;
    __syncthreads();
    float inv = 1.f / (red[0] + red[1] + red[2] + red[3]);
    // PV: split t-range across 2 halves of the block
    int half = tid >> 7;
    int d = tid & 127;
    if (d < HD) {
        const float* vbase = qkv + 768 + h * HD + d;
        float acc = 0.f;
        int t0 = half * 512;
        for (int t = t0; t < t0 + 512; t++)
            acc += ps[t] * vbase[(size_t)t * 1152];
        pv[half][d] = acc;
    }
    __syncthreads();
    if (tid < HD)
        ao[(size_t)row * C_S + h * HD + tid] = (pv[0][tid] + pv[1][tid]) * inv;
}

// ---------------------------------------------------------------------------
// token head: tout[t][j] = tf[t] . co_w[j] + co_b[j]
__global__ __launch_bounds__(64) void k_tokout(
    const float* __restrict__ tf, const float* __restrict__ co_w,
    const float* __restrict__ co_b, float* __restrict__ tout)
{
    int t = blockIdx.x, lane = threadIdx.x;
    float a0 = 0.f, a1 = 0.f, a2 = 0.f;
    for (int c = lane; c < C_S; c += 64) {
        float v = tf[(size_t)t * C_S + c];
        a0 += v * co_w[c];
        a1 += v * co_w[C_S + c];
        a2 += v * co_w[2 * C_S + c];
    }
    #pragma unroll
    for (int off = 32; off > 0; off >>= 1) {
        a0 += __shfl_down(a0, off);
        a1 += __shfl_down(a1, off);
        a2 += __shfl_down(a2, off);
    }
    if (lane == 0) {
        tout[t * 3 + 0] = a0 + co_b[0];
        tout[t * 3 + 1] = a1 + co_b[1];
        tout[t * 3 + 2] = a2 + co_b[2];
    }
}

__global__ __launch_bounds__(256) void k_gather(
    const float* __restrict__ tout, const int* __restrict__ idx,
    float* __restrict__ out)
{
    int e = blockIdx.x * 256 + threadIdx.x;
    if (e < N_ATOM * 3) {
        int a = e / 3, j = e - a * 3;
        out[e] = tout[idx[a] * 3 + j];
    }
}

// ---------------------------------------------------------------------------
extern "C" void kernel_launch(void* const* d_in, const int* in_sizes, int n_in,
                              void* d_out, int out_size, void* d_ws, size_t ws_size,
                              hipStream_t stream)
{
    const float* x_noisy   = (const float*)d_in[0];
    const float* s         = (const float*)d_in[1];
    // d_in[2] = z : dead code in the reference (z_cond unused) -> never read
    const float* sigma     = (const float*)d_in[3];
    const int*   a2t       = (const int*)d_in[4];
    const float* fourier_w = (const float*)d_in[5];
    const float* fourier_b = (const float*)d_in[6];
    const float* ns_w      = (const float*)d_in[7];
    const float* ns_b      = (const float*)d_in[8];
    const float* lns_g     = (const float*)d_in[11];
    const float* lns_b     = (const float*)d_in[12];
    const float* ce_w      = (const float*)d_in[15];
    const float* ce_b      = (const float*)d_in[16];
    const float* in_w      = (const float*)d_in[17];
    const float* in_b      = (const float*)d_in[18];
    const float* out_w     = (const float*)d_in[19];
    const float* out_b     = (const float*)d_in[20];
    const float* ffln_g    = (const float*)d_in[21];
    const float* ffln_b    = (const float*)d_in[22];
    const float* ff1_w     = (const float*)d_in[23];
    const float* ff1_b     = (const float*)d_in[24];
    const float* ff2_w     = (const float*)d_in[25];
    const float* ff2_b     = (const float*)d_in[26];
    const float* co_w      = (const float*)d_in[27];
    const float* co_b      = (const float*)d_in[28];

    float* ws  = (float*)d_ws;
    float* out = (float*)d_out;

    hipMemsetAsync(ws + OFF_SEGX, 0, 4096 * sizeof(float), stream);

    hipLaunchKernelGGL(k_setup, dim3(1), dim3(384), 0, stream,
                       sigma, fourier_w, fourier_b, ns_w, ns_b,
                       ws + OFF_NOISE, ws + OFF_NSPROJ);
    hipLaunchKernelGGL(k_segsum, dim3((N_ATOM + 255) / 256), dim3(256), 0, stream,
                       x_noisy, a2t, ws + OFF_SEGX);
    hipLaunchKernelGGL(k_tokenfeat, dim3(N_TOK), dim3(128), 0, stream,
                       s, ws + OFF_SEGX, ws + OFF_NSPROJ, lns_g, lns_b,
                       ce_w, ce_b, ws + OFF_TF1);
    // qkv = tf1 @ in_w^T + in_b    [1024,1152]
    hipLaunchKernelGGL((k_gemm<0, false>), dim3(1152 / 64, 1024 / 64), dim3(256), 0, stream,
                       ws + OFF_TF1, in_w, in_b, nullptr, ws + OFF_QKV, 1024, 1152, 384);
    // attention
    hipLaunchKernelGGL(k_attn, dim3(N_TOK, NH), dim3(256), 0, stream,
                       ws + OFF_QKV, ws + OFF_AO);
    // tf2 = tf1 + ao @ out_w^T + out_b
    hipLaunchKernelGGL((k_gemm<0, true>), dim3(384 / 64, 1024 / 64), dim3(256), 0, stream,
                       ws + OFF_AO, out_w, out_b, ws + OFF_TF1, ws + OFF_TF2, 1024, 384, 384);
    // lnh = LN(tf2)
    hipLaunchKernelGGL(k_ln, dim3(N_TOK), dim3(128), 0, stream,
                       ws + OFF_TF2, ffln_g, ffln_b, ws + OFF_LNH);
    // h1 = silu(lnh @ ff1_w^T + ff1_b)   [1024,1536]
    hipLaunchKernelGGL((k_gemm<1, false>), dim3(1536 / 64, 1024 / 64), dim3(256), 0, stream,
                       ws + OFF_LNH, ff1_w, ff1_b, nullptr, ws + OFF_H1, 1024, 1536, 384);
    // tf3 = tf2 + h1 @ ff2_w^T + ff2_b
    hipLaunchKernelGGL((k_gemm<0, true>), dim3(384 / 64, 1024 / 64), dim3(256), 0, stream,
                       ws + OFF_H1, ff2_w, ff2_b, ws + OFF_TF2, ws + OFF_TF3, 1024, 384, 1536);
    // token head + gather
    hipLaunchKernelGGL(k_tokout, dim3(N_TOK), dim3(64), 0, stream,
                       ws + OFF_TF3, co_w, co_b, ws + OFF_TOUT);
    hipLaunchKernelGGL(k_gather, dim3((N_ATOM * 3 + 255) / 256), dim3(256), 0, stream,
                       ws + OFF_TOUT, a2t, out);
}

// Round 2
// 331.549 us; speedup vs baseline: 1.6559x; 1.6559x over previous
//
#include <hip/hip_runtime.h>
#include <hip/hip_bf16.h>
#include <math.h>

#define N_TOK 1024
#define N_ATOM 24576
#define C_S 384
#define FDIM 256
#define NH 4
#define HD 96

// ---- workspace layout (float offsets, all 16B-aligned) ----
#define OFF_SEGX   0u          // 1024*4  (sum x,y,z,count)
#define OFF_NOISE  4096u       // 256
#define OFF_NSPROJ 4352u       // 384
#define OFF_TF1    4736u       // 1024*384
#define OFF_QKV    397952u     // 1024*1152
#define OFF_AO     1577600u    // 1024*384
#define OFF_TF2    1970816u    // 1024*384
#define OFF_LNH    2364032u    // 1024*384
#define OFF_H1     2757248u    // 1024*1536
#define OFF_TF3    4330112u    // 1024*384
#define OFF_TOUT   4723328u    // 1024*3

// ---------------------------------------------------------------------------
__global__ __launch_bounds__(256) void k_zero(float* __restrict__ p, int n)
{
    int i = blockIdx.x * 256 + threadIdx.x;
    if (i < n) p[i] = 0.f;
}

// small setup: fourier embedding -> noise [256] -> ns_proj [384]
__global__ __launch_bounds__(384) void k_setup(
    const float* __restrict__ sigma,
    const float* __restrict__ fw, const float* __restrict__ fb,
    const float* __restrict__ nsw, const float* __restrict__ nsb,
    float* __restrict__ noise_out, float* __restrict__ nsproj_out)
{
    __shared__ float emb[256];
    __shared__ float noise[256];
    int tid = threadIdx.x;
    float sg = sigma[0];
    if (tid < 128) {
        float fr = expf(-logf(1000.f) * (float)tid / 128.f);
        float x = sg * fr;
        emb[tid]       = cosf(x);
        emb[tid + 128] = sinf(x);
    }
    __syncthreads();
    if (tid < 256) {
        const float* wr = fw + (size_t)tid * 256;
        float acc = fb[tid];
        for (int i = 0; i < 256; i++) acc += emb[i] * wr[i];
        noise[tid] = acc;
        noise_out[tid] = acc;
    }
    __syncthreads();
    if (tid < 384) {
        const float* wr = nsw + (size_t)tid * 256;
        float acc = nsb[tid];
        for (int i = 0; i < 256; i++) acc += noise[i] * wr[i];
        nsproj_out[tid] = acc;
    }
}

// ---------------------------------------------------------------------------
// segment sum of raw coords + counts (project AFTER the mean: 100x less work)
__global__ __launch_bounds__(256) void k_segsum(
    const float* __restrict__ x, const int* __restrict__ idx,
    float* __restrict__ segx)
{
    int a = blockIdx.x * 256 + threadIdx.x;
    if (a < N_ATOM) {
        int t = idx[a];
        atomicAdd(&segx[t * 4 + 0], x[a * 3 + 0]);
        atomicAdd(&segx[t * 4 + 1], x[a * 3 + 1]);
        atomicAdd(&segx[t * 4 + 2], x[a * 3 + 2]);
        atomicAdd(&segx[t * 4 + 3], 1.f);
    }
}

// ---------------------------------------------------------------------------
__device__ inline float blockReduceSum128(float v, volatile float* sm)
{
    #pragma unroll
    for (int off = 32; off > 0; off >>= 1) v += __shfl_down(v, off);
    if ((threadIdx.x & 63) == 0) sm[threadIdx.x >> 6] = v;
    __syncthreads();
    float r = sm[0] + sm[1];
    __syncthreads();
    return r;
}

// token_feat = LN(s)*g+b + ns_proj + (cnt>0 ? mean_x@ce_w.T + ce_b : 0)
__global__ __launch_bounds__(128) void k_tokenfeat(
    const float* __restrict__ s, const float* __restrict__ segx,
    const float* __restrict__ nsproj,
    const float* __restrict__ g, const float* __restrict__ b,
    const float* __restrict__ ce_w, const float* __restrict__ ce_b,
    float* __restrict__ tf)
{
    __shared__ float sm[2];
    int t = blockIdx.x, tid = threadIdx.x;
    const float* sr = s + (size_t)t * C_S;
    float x0 = sr[tid], x1 = sr[tid + 128], x2 = sr[tid + 256];
    float total = blockReduceSum128(x0 + x1 + x2, sm);
    float mean = total * (1.f / 384.f);
    float d0 = x0 - mean, d1 = x1 - mean, d2 = x2 - mean;
    float vtot = blockReduceSum128(d0 * d0 + d1 * d1 + d2 * d2, sm);
    float inv = rsqrtf(vtot * (1.f / 384.f) + 1e-5f);
    float cnt = segx[t * 4 + 3];
    float mx0 = 0.f, mx1 = 0.f, mx2 = 0.f;
    int has = cnt > 0.f;
    if (has) {
        float ic = 1.f / cnt;
        mx0 = segx[t * 4 + 0] * ic;
        mx1 = segx[t * 4 + 1] * ic;
        mx2 = segx[t * 4 + 2] * ic;
    }
    float xs[3] = {d0, d1, d2};
    #pragma unroll
    for (int l = 0; l < 3; l++) {
        int c = tid + l * 128;
        float ln = xs[l] * inv * g[c] + b[c];
        float coord = 0.f;
        if (has)
            coord = mx0 * ce_w[c * 3 + 0] + mx1 * ce_w[c * 3 + 1]
                  + mx2 * ce_w[c * 3 + 2] + ce_b[c];
        tf[(size_t)t * C_S + c] = ln + nsproj[c] + coord;
    }
}

// plain LN (for ffln)
__global__ __launch_bounds__(128) void k_ln(
    const float* __restrict__ in, const float* __restrict__ g,
    const float* __restrict__ b, float* __restrict__ out)
{
    __shared__ float sm[2];
    int t = blockIdx.x, tid = threadIdx.x;
    const float* sr = in + (size_t)t * C_S;
    float x0 = sr[tid], x1 = sr[tid + 128], x2 = sr[tid + 256];
    float total = blockReduceSum128(x0 + x1 + x2, sm);
    float mean = total * (1.f / 384.f);
    float d0 = x0 - mean, d1 = x1 - mean, d2 = x2 - mean;
    float vtot = blockReduceSum128(d0 * d0 + d1 * d1 + d2 * d2, sm);
    float inv = rsqrtf(vtot * (1.f / 384.f) + 1e-5f);
    float xs[3] = {d0, d1, d2};
    #pragma unroll
    for (int l = 0; l < 3; l++) {
        int c = tid + l * 128;
        out[(size_t)t * C_S + c] = xs[l] * inv * g[c] + b[c];
    }
}

// ---------------------------------------------------------------------------
// C[M,N] = act(A[M,K] @ W[N,K]^T + bias) (+ res). 64x64 tile, BK=32, 4x4/thread,
// b128 LDS fragment reads (pad 68 keeps 16B alignment, conflict-free reads).
template <int ACT, bool RES>
__global__ __launch_bounds__(256) void k_gemm(
    const float* __restrict__ A, const float* __restrict__ W,
    const float* __restrict__ bias, const float* __restrict__ res,
    float* __restrict__ C, int M, int N, int K)
{
    __shared__ float As[32][68];
    __shared__ float Bs[32][68];
    int bm = blockIdx.y * 64;
    int bn = blockIdx.x * 64;
    int tid = threadIdx.x;
    int tx = tid & 15, ty = tid >> 4;   // out: rows bm+4ty.., cols bn+4tx..
    float acc[4][4] = {};
    for (int k0 = 0; k0 < K; k0 += 32) {
        #pragma unroll
        for (int i = 0; i < 2; ++i) {
            int f = tid + i * 256;           // 512 float4 per matrix
            int r = f >> 3, c4 = (f & 7) << 2;
            float4 av = *(const float4*)(A + (size_t)(bm + r) * K + k0 + c4);
            float4 bv = *(const float4*)(W + (size_t)(bn + r) * K + k0 + c4);
            As[c4 + 0][r] = av.x; As[c4 + 1][r] = av.y;
            As[c4 + 2][r] = av.z; As[c4 + 3][r] = av.w;
            Bs[c4 + 0][r] = bv.x; Bs[c4 + 1][r] = bv.y;
            Bs[c4 + 2][r] = bv.z; Bs[c4 + 3][r] = bv.w;
        }
        __syncthreads();
        #pragma unroll
        for (int k = 0; k < 32; ++k) {
            float4 a = *(const float4*)&As[k][ty << 2];
            float4 b = *(const float4*)&Bs[k][tx << 2];
            acc[0][0] += a.x * b.x; acc[0][1] += a.x * b.y;
            acc[0][2] += a.x * b.z; acc[0][3] += a.x * b.w;
            acc[1][0] += a.y * b.x; acc[1][1] += a.y * b.y;
            acc[1][2] += a.y * b.z; acc[1][3] += a.y * b.w;
            acc[2][0] += a.z * b.x; acc[2][1] += a.z * b.y;
            acc[2][2] += a.z * b.z; acc[2][3] += a.z * b.w;
            acc[3][0] += a.w * b.x; acc[3][1] += a.w * b.y;
            acc[3][2] += a.w * b.z; acc[3][3] += a.w * b.w;
        }
        __syncthreads();
    }
    float b0 = bias[bn + 4 * tx + 0], b1 = bias[bn + 4 * tx + 1];
    float b2 = bias[bn + 4 * tx + 2], b3 = bias[bn + 4 * tx + 3];
    #pragma unroll
    for (int ii = 0; ii < 4; ii++) {
        int m = bm + 4 * ty + ii;
        int n = bn + 4 * tx;
        float4 v;
        v.x = acc[ii][0] + b0; v.y = acc[ii][1] + b1;
        v.z = acc[ii][2] + b2; v.w = acc[ii][3] + b3;
        if (ACT == 1) {
            v.x = v.x / (1.f + __expf(-v.x)); v.y = v.y / (1.f + __expf(-v.y));
            v.z = v.z / (1.f + __expf(-v.z)); v.w = v.w / (1.f + __expf(-v.w));
        }
        if (RES) {
            float4 r = *(const float4*)(res + (size_t)m * N + n);
            v.x += r.x; v.y += r.y; v.z += r.z; v.w += r.w;
        }
        *(float4*)(C + (size_t)m * N + n) = v;
    }
}

// ---------------------------------------------------------------------------
// flash-style attention: block = (16 Q-rows, head), K/V tiled 64 tokens in LDS,
// online softmax in registers (wave w owns rows w+4k -> pure wave reduces).
#define QBLK 16
#define TBLK 64

__global__ __launch_bounds__(256) void k_attn(
    const float* __restrict__ qkv, float* __restrict__ ao)
{
    __shared__ float Qs[QBLK][96];       // broadcast reads -> no pad needed
    __shared__ float Ks[TBLK][100];      // pad 100: b128 lane-starts 4t%32 (ideal)
    __shared__ float Vs[TBLK][96];       // lanes share t -> quad-spread, free
    __shared__ float Ps[QBLK][65];       // pad 65: scalar r/w conflict-free
    __shared__ float scl[QBLK];
    __shared__ float ll[QBLK];

    int tid = threadIdx.x;
    int row0 = blockIdx.x * QBLK;
    int h = blockIdx.y;
    const float scale = 0.1020620726f;   // 1/sqrt(96)

    // stage Q once: 16 rows x 24 float4
    for (int f = tid; f < QBLK * 24; f += 256) {
        int r = f / 24, c = f % 24;
        *(float4*)&Qs[r][c * 4] =
            *(const float4*)(qkv + (size_t)(row0 + r) * 1152 + h * 96 + c * 4);
    }

    int t = tid & 63;                    // score column within tile
    int w = tid >> 6;                    // wave id: owns rows w+4k, k=0..3
    int pr = w + 4 * ((tid & 63) >> 4);  // PV row (same wave's rows)
    int ds = (tid & 15) * 6;             // PV d-slice: 6 floats

    float m[4], lsum[4], o[6];
    #pragma unroll
    for (int k = 0; k < 4; k++) { m[k] = -1e30f; lsum[k] = 0.f; }
    #pragma unroll
    for (int i = 0; i < 6; i++) o[i] = 0.f;

    for (int tile = 0; tile < N_TOK / TBLK; ++tile) {
        int t0 = tile * TBLK;
        __syncthreads();                 // LDS reuse fence (covers Q 1st iter)
        for (int f = tid; f < TBLK * 24; f += 256) {
            int r = f / 24, c = f % 24;
            const float* src = qkv + (size_t)(t0 + r) * 1152 + 384 + h * 96 + c * 4;
            *(float4*)&Ks[r][c * 4] = *(const float4*)src;
            *(float4*)&Vs[r][c * 4] = *(const float4*)(src + 384);
        }
        __syncthreads();

        // ---- scores: s[k] = Q[w+4k] . K[t] ----
        float s[4] = {0.f, 0.f, 0.f, 0.f};
        #pragma unroll
        for (int d4 = 0; d4 < 24; ++d4) {
            float4 kv = *(const float4*)&Ks[t][d4 * 4];
            #pragma unroll
            for (int k = 0; k < 4; ++k) {
                float4 qv = *(const float4*)&Qs[w + 4 * k][d4 * 4];
                s[k] += qv.x * kv.x + qv.y * kv.y + qv.z * kv.z + qv.w * kv.w;
            }
        }
        // ---- online softmax update (per wave-owned row) ----
        #pragma unroll
        for (int k = 0; k < 4; ++k) {
            float sv = s[k] * scale;
            float tmax = sv;
            #pragma unroll
            for (int off = 32; off > 0; off >>= 1)
                tmax = fmaxf(tmax, __shfl_xor(tmax, off));
            float mnew = fmaxf(m[k], tmax);
            float p = __expf(sv - mnew);
            float ts = p;
            #pragma unroll
            for (int off = 32; off > 0; off >>= 1)
                ts += __shfl_xor(ts, off);
            float sc = __expf(m[k] - mnew);
            lsum[k] = lsum[k] * sc + ts;
            m[k] = mnew;
            Ps[w + 4 * k][t] = p;
            if (t == 0) scl[w + 4 * k] = sc;
        }
        // ---- PV (wave-local LDS handoff, no barrier needed) ----
        float sc_mine = scl[pr];
        #pragma unroll
        for (int i = 0; i < 6; i++) o[i] *= sc_mine;
        for (int tt = 0; tt < TBLK; ++tt) {
            float p = Ps[pr][tt];
            float2 v0 = *(const float2*)&Vs[tt][ds + 0];
            float2 v1 = *(const float2*)&Vs[tt][ds + 2];
            float2 v2 = *(const float2*)&Vs[tt][ds + 4];
            o[0] += p * v0.x; o[1] += p * v0.y;
            o[2] += p * v1.x; o[3] += p * v1.y;
            o[4] += p * v2.x; o[5] += p * v2.y;
        }
    }
    #pragma unroll
    for (int k = 0; k < 4; ++k)
        if (t == 0) ll[w + 4 * k] = lsum[k];
    float inv = 1.f / ll[pr];
    float* dst = ao + (size_t)(row0 + pr) * C_S + h * 96 + ds;
    float2 r0, r1, r2;
    r0.x = o[0] * inv; r0.y = o[1] * inv;
    r1.x = o[2] * inv; r1.y = o[3] * inv;
    r2.x = o[4] * inv; r2.y = o[5] * inv;
    *(float2*)(dst + 0) = r0;
    *(float2*)(dst + 2) = r1;
    *(float2*)(dst + 4) = r2;
}

// ---------------------------------------------------------------------------
// token head: tout[t][j] = tf[t] . co_w[j] + co_b[j]
__global__ __launch_bounds__(64) void k_tokout(
    const float* __restrict__ tf, const float* __restrict__ co_w,
    const float* __restrict__ co_b, float* __restrict__ tout)
{
    int t = blockIdx.x, lane = threadIdx.x;
    float a0 = 0.f, a1 = 0.f, a2 = 0.f;
    for (int c = lane; c < C_S; c += 64) {
        float v = tf[(size_t)t * C_S + c];
        a0 += v * co_w[c];
        a1 += v * co_w[C_S + c];
        a2 += v * co_w[2 * C_S + c];
    }
    #pragma unroll
    for (int off = 32; off > 0; off >>= 1) {
        a0 += __shfl_down(a0, off);
        a1 += __shfl_down(a1, off);
        a2 += __shfl_down(a2, off);
    }
    if (lane == 0) {
        tout[t * 3 + 0] = a0 + co_b[0];
        tout[t * 3 + 1] = a1 + co_b[1];
        tout[t * 3 + 2] = a2 + co_b[2];
    }
}

__global__ __launch_bounds__(256) void k_gather(
    const float* __restrict__ tout, const int* __restrict__ idx,
    float* __restrict__ out)
{
    int e = blockIdx.x * 256 + threadIdx.x;
    if (e < N_ATOM * 3) {
        int a = e / 3, j = e - a * 3;
        out[e] = tout[idx[a] * 3 + j];
    }
}

// ---------------------------------------------------------------------------
extern "C" void kernel_launch(void* const* d_in, const int* in_sizes, int n_in,
                              void* d_out, int out_size, void* d_ws, size_t ws_size,
                              hipStream_t stream)
{
    const float* x_noisy   = (const float*)d_in[0];
    const float* s         = (const float*)d_in[1];
    // d_in[2] = z : dead code in the reference (z_cond unused) -> never read
    const float* sigma     = (const float*)d_in[3];
    const int*   a2t       = (const int*)d_in[4];
    const float* fourier_w = (const float*)d_in[5];
    const float* fourier_b = (const float*)d_in[6];
    const float* ns_w      = (const float*)d_in[7];
    const float* ns_b      = (const float*)d_in[8];
    const float* lns_g     = (const float*)d_in[11];
    const float* lns_b     = (const float*)d_in[12];
    const float* ce_w      = (const float*)d_in[15];
    const float* ce_b      = (const float*)d_in[16];
    const float* in_w      = (const float*)d_in[17];
    const float* in_b      = (const float*)d_in[18];
    const float* out_w     = (const float*)d_in[19];
    const float* out_b     = (const float*)d_in[20];
    const float* ffln_g    = (const float*)d_in[21];
    const float* ffln_b    = (const float*)d_in[22];
    const float* ff1_w     = (const float*)d_in[23];
    const float* ff1_b     = (const float*)d_in[24];
    const float* ff2_w     = (const float*)d_in[25];
    const float* ff2_b     = (const float*)d_in[26];
    const float* co_w      = (const float*)d_in[27];
    const float* co_b      = (const float*)d_in[28];

    float* ws  = (float*)d_ws;
    float* out = (float*)d_out;

    hipLaunchKernelGGL(k_zero, dim3(16), dim3(256), 0, stream,
                       ws + OFF_SEGX, 4096);
    hipLaunchKernelGGL(k_setup, dim3(1), dim3(384), 0, stream,
                       sigma, fourier_w, fourier_b, ns_w, ns_b,
                       ws + OFF_NOISE, ws + OFF_NSPROJ);
    hipLaunchKernelGGL(k_segsum, dim3((N_ATOM + 255) / 256), dim3(256), 0, stream,
                       x_noisy, a2t, ws + OFF_SEGX);
    hipLaunchKernelGGL(k_tokenfeat, dim3(N_TOK), dim3(128), 0, stream,
                       s, ws + OFF_SEGX, ws + OFF_NSPROJ, lns_g, lns_b,
                       ce_w, ce_b, ws + OFF_TF1);
    // qkv = tf1 @ in_w^T + in_b    [1024,1152]
    hipLaunchKernelGGL((k_gemm<0, false>), dim3(1152 / 64, 1024 / 64), dim3(256), 0, stream,
                       ws + OFF_TF1, in_w, in_b, nullptr, ws + OFF_QKV, 1024, 1152, 384);
    // attention
    hipLaunchKernelGGL(k_attn, dim3(N_TOK / QBLK, NH), dim3(256), 0, stream,
                       ws + OFF_QKV, ws + OFF_AO);
    // tf2 = tf1 + ao @ out_w^T + out_b
    hipLaunchKernelGGL((k_gemm<0, true>), dim3(384 / 64, 1024 / 64), dim3(256), 0, stream,
                       ws + OFF_AO, out_w, out_b, ws + OFF_TF1, ws + OFF_TF2, 1024, 384, 384);
    // lnh = LN(tf2)
    hipLaunchKernelGGL(k_ln, dim3(N_TOK), dim3(128), 0, stream,
                       ws + OFF_TF2, ffln_g, ffln_b, ws + OFF_LNH);
    // h1 = silu(lnh @ ff1_w^T + ff1_b)   [1024,1536]
    hipLaunchKernelGGL((k_gemm<1, false>), dim3(1536 / 64, 1024 / 64), dim3(256), 0, stream,
                       ws + OFF_LNH, ff1_w, ff1_b, nullptr, ws + OFF_H1, 1024, 1536, 384);
    // tf3 = tf2 + h1 @ ff2_w^T + ff2_b
    hipLaunchKernelGGL((k_gemm<0, true>), dim3(384 / 64, 1024 / 64), dim3(256), 0, stream,
                       ws + OFF_H1, ff2_w, ff2_b, ws + OFF_TF2, ws + OFF_TF3, 1024, 384, 1536);
    // token head + gather
    hipLaunchKernelGGL(k_tokout, dim3(N_TOK), dim3(64), 0, stream,
                       ws + OFF_TF3, co_w, co_b, ws + OFF_TOUT);
    hipLaunchKernelGGL(k_gather, dim3((N_ATOM * 3 + 255) / 256), dim3(256), 0, stream,
                       ws + OFF_TOUT, a2t, out);
}

// Round 3
// 225.675 us; speedup vs baseline: 2.4327x; 1.4691x over previous
//
#include <hip/hip_runtime.h>
#include <hip/hip_bf16.h>
#include <math.h>

#define N_TOK 1024
#define N_ATOM 24576
#define C_S 384
#define FDIM 256
#define NH 4
#define HD 96

typedef __attribute__((ext_vector_type(8))) short short8;   // 8 bf16 (4 VGPR)
typedef __attribute__((ext_vector_type(4))) float f32x4;

// ---- workspace layout (float offsets, all 16B-aligned) ----
#define OFF_SEGX   0u          // 1024*4  (sum x,y,z,count)
#define OFF_NOISE  4096u       // 256
#define OFF_NSPROJ 4352u       // 384
#define OFF_TF1    4736u       // 1024*384
#define OFF_QKV    397952u     // 1024*1152
#define OFF_AO     1577600u    // 1024*384
#define OFF_TF2    1970816u    // 1024*384
#define OFF_LNH    2364032u    // 1024*384
#define OFF_H1     2757248u    // 1024*1536
#define OFF_TF3    4330112u    // 1024*384
#define OFF_TOUT   4723328u    // 1024*3

// ---------------------------------------------------------------------------
// setup: zero segx + fourier embedding -> noise [256] -> ns_proj [384]
__global__ __launch_bounds__(384) void k_setup(
    const float* __restrict__ sigma,
    const float* __restrict__ fw, const float* __restrict__ fb,
    const float* __restrict__ nsw, const float* __restrict__ nsb,
    float* __restrict__ noise_out, float* __restrict__ nsproj_out,
    float* __restrict__ segx)
{
    __shared__ float emb[256];
    __shared__ float noise[256];
    int tid = threadIdx.x;
    for (int i = tid; i < 4096; i += 384) segx[i] = 0.f;   // zero for k_segsum
    float sg = sigma[0];
    if (tid < 128) {
        float fr = expf(-logf(1000.f) * (float)tid / 128.f);
        float x = sg * fr;
        emb[tid]       = cosf(x);
        emb[tid + 128] = sinf(x);
    }
    __syncthreads();
    if (tid < 256) {
        const float* wr = fw + (size_t)tid * 256;
        float acc = fb[tid];
        for (int i = 0; i < 256; i++) acc += emb[i] * wr[i];
        noise[tid] = acc;
        noise_out[tid] = acc;
    }
    __syncthreads();
    if (tid < 384) {
        const float* wr = nsw + (size_t)tid * 256;
        float acc = nsb[tid];
        for (int i = 0; i < 256; i++) acc += noise[i] * wr[i];
        nsproj_out[tid] = acc;
    }
}

// ---------------------------------------------------------------------------
// segment sum of raw coords + counts (project AFTER the mean: 100x less work)
__global__ __launch_bounds__(256) void k_segsum(
    const float* __restrict__ x, const int* __restrict__ idx,
    float* __restrict__ segx)
{
    int a = blockIdx.x * 256 + threadIdx.x;
    if (a < N_ATOM) {
        int t = idx[a];
        atomicAdd(&segx[t * 4 + 0], x[a * 3 + 0]);
        atomicAdd(&segx[t * 4 + 1], x[a * 3 + 1]);
        atomicAdd(&segx[t * 4 + 2], x[a * 3 + 2]);
        atomicAdd(&segx[t * 4 + 3], 1.f);
    }
}

// ---------------------------------------------------------------------------
__device__ inline float blockReduceSum128(float v, volatile float* sm)
{
    #pragma unroll
    for (int off = 32; off > 0; off >>= 1) v += __shfl_down(v, off);
    if ((threadIdx.x & 63) == 0) sm[threadIdx.x >> 6] = v;
    __syncthreads();
    float r = sm[0] + sm[1];
    __syncthreads();
    return r;
}

// token_feat = LN(s)*g+b + ns_proj + (cnt>0 ? mean_x@ce_w.T + ce_b : 0)
__global__ __launch_bounds__(128) void k_tokenfeat(
    const float* __restrict__ s, const float* __restrict__ segx,
    const float* __restrict__ nsproj,
    const float* __restrict__ g, const float* __restrict__ b,
    const float* __restrict__ ce_w, const float* __restrict__ ce_b,
    float* __restrict__ tf)
{
    __shared__ float sm[2];
    int t = blockIdx.x, tid = threadIdx.x;
    const float* sr = s + (size_t)t * C_S;
    float x0 = sr[tid], x1 = sr[tid + 128], x2 = sr[tid + 256];
    float total = blockReduceSum128(x0 + x1 + x2, sm);
    float mean = total * (1.f / 384.f);
    float d0 = x0 - mean, d1 = x1 - mean, d2 = x2 - mean;
    float vtot = blockReduceSum128(d0 * d0 + d1 * d1 + d2 * d2, sm);
    float inv = rsqrtf(vtot * (1.f / 384.f) + 1e-5f);
    float cnt = segx[t * 4 + 3];
    float mx0 = 0.f, mx1 = 0.f, mx2 = 0.f;
    int has = cnt > 0.f;
    if (has) {
        float ic = 1.f / cnt;
        mx0 = segx[t * 4 + 0] * ic;
        mx1 = segx[t * 4 + 1] * ic;
        mx2 = segx[t * 4 + 2] * ic;
    }
    float xs[3] = {d0, d1, d2};
    #pragma unroll
    for (int l = 0; l < 3; l++) {
        int c = tid + l * 128;
        float ln = xs[l] * inv * g[c] + b[c];
        float coord = 0.f;
        if (has)
            coord = mx0 * ce_w[c * 3 + 0] + mx1 * ce_w[c * 3 + 1]
                  + mx2 * ce_w[c * 3 + 2] + ce_b[c];
        tf[(size_t)t * C_S + c] = ln + nsproj[c] + coord;
    }
}

// plain LN (for ffln)
__global__ __launch_bounds__(128) void k_ln(
    const float* __restrict__ in, const float* __restrict__ g,
    const float* __restrict__ b, float* __restrict__ out)
{
    __shared__ float sm[2];
    int t = blockIdx.x, tid = threadIdx.x;
    const float* sr = in + (size_t)t * C_S;
    float x0 = sr[tid], x1 = sr[tid + 128], x2 = sr[tid + 256];
    float total = blockReduceSum128(x0 + x1 + x2, sm);
    float mean = total * (1.f / 384.f);
    float d0 = x0 - mean, d1 = x1 - mean, d2 = x2 - mean;
    float vtot = blockReduceSum128(d0 * d0 + d1 * d1 + d2 * d2, sm);
    float inv = rsqrtf(vtot * (1.f / 384.f) + 1e-5f);
    float xs[3] = {d0, d1, d2};
    #pragma unroll
    for (int l = 0; l < 3; l++) {
        int c = tid + l * 128;
        out[(size_t)t * C_S + c] = xs[l] * inv * g[c] + b[c];
    }
}

// ---------------------------------------------------------------------------
// bf16 MFMA GEMM: C[M,N] = act(A[M,K] @ W[N,K]^T + bias) (+ res).
// 64x64 tile, BK=64, 4 waves x (32x32 out each), f32 global -> bf16 LDS.
__device__ inline __hip_bfloat16 f2bf(float x) { return __float2bfloat16(x); }

union BFPack { short8 v; __hip_bfloat16 h[8]; };

__device__ inline short8 pack8(float4 a, float4 b)
{
    BFPack p;
    p.h[0] = f2bf(a.x); p.h[1] = f2bf(a.y); p.h[2] = f2bf(a.z); p.h[3] = f2bf(a.w);
    p.h[4] = f2bf(b.x); p.h[5] = f2bf(b.y); p.h[6] = f2bf(b.z); p.h[7] = f2bf(b.w);
    return p.v;
}

template <int ACT, bool RES>
__global__ __launch_bounds__(256) void k_gemm(
    const float* __restrict__ A, const float* __restrict__ W,
    const float* __restrict__ bias, const float* __restrict__ res,
    float* __restrict__ C, int M, int N, int K)
{
    __shared__ __hip_bfloat16 As[64][72];   // 144B rows: 16B-aligned, uniform banks
    __shared__ __hip_bfloat16 Bs[64][72];

    int tid = threadIdx.x;
    int bm = blockIdx.y * 64, bn = blockIdx.x * 64;
    int w = tid >> 6, lane = tid & 63;
    int wr = (w >> 1) * 32, wc = (w & 1) * 32;   // wave's 32x32 sub-tile
    int fr = lane & 15, kg = lane >> 4;          // fragment row / k-group

    int sr = tid >> 2;            // staging row 0..63
    int sc = (tid & 3) * 16;      // staging col 0,16,32,48

    f32x4 acc[2][2] = {};

    for (int k0 = 0; k0 < K; k0 += 64) {
        const float* ag = A + (size_t)(bm + sr) * K + k0 + sc;
        const float* wg = W + (size_t)(bn + sr) * K + k0 + sc;
        float4 a0 = *(const float4*)(ag + 0),  a1 = *(const float4*)(ag + 4);
        float4 a2 = *(const float4*)(ag + 8),  a3 = *(const float4*)(ag + 12);
        float4 b0 = *(const float4*)(wg + 0),  b1 = *(const float4*)(wg + 4);
        float4 b2 = *(const float4*)(wg + 8),  b3 = *(const float4*)(wg + 12);
        __syncthreads();   // previous iter's reads done before overwrite
        *(short8*)&As[sr][sc + 0] = pack8(a0, a1);
        *(short8*)&As[sr][sc + 8] = pack8(a2, a3);
        *(short8*)&Bs[sr][sc + 0] = pack8(b0, b1);
        *(short8*)&Bs[sr][sc + 8] = pack8(b2, b3);
        __syncthreads();

        short8 af[2][2], bf[2][2];
        #pragma unroll
        for (int i = 0; i < 2; ++i)
            #pragma unroll
            for (int kh = 0; kh < 2; ++kh) {
                af[i][kh] = *(const short8*)&As[wr + i * 16 + fr][kh * 32 + kg * 8];
                bf[i][kh] = *(const short8*)&Bs[wc + i * 16 + fr][kh * 32 + kg * 8];
            }
        #pragma unroll
        for (int kh = 0; kh < 2; ++kh)
            #pragma unroll
            for (int i = 0; i < 2; ++i)
                #pragma unroll
                for (int j = 0; j < 2; ++j)
                    acc[i][j] = __builtin_amdgcn_mfma_f32_16x16x32_bf16(
                        af[i][kh], bf[j][kh], acc[i][j], 0, 0, 0);
    }

    // epilogue: C/D layout col=lane&15, row=(lane>>4)*4+reg  [m89-verified]
    #pragma unroll
    for (int i = 0; i < 2; ++i) {
        #pragma unroll
        for (int j = 0; j < 2; ++j) {
            int n = bn + wc + j * 16 + fr;
            float bv = bias[n];
            #pragma unroll
            for (int r = 0; r < 4; ++r) {
                int m = bm + wr + i * 16 + kg * 4 + r;
                float v = acc[i][j][r] + bv;
                if (ACT == 1) v = v / (1.f + __expf(-v));   // silu
                if (RES) v += res[(size_t)m * N + n];
                C[(size_t)m * N + n] = v;
            }
        }
    }
}

// ---------------------------------------------------------------------------
// flash-style attention (f32): block = (16 Q-rows, head), K/V tiles in LDS,
// online softmax in registers (wave w owns rows w+4k -> pure wave reduces).
#define QBLK 16
#define TBLK 64

__global__ __launch_bounds__(256) void k_attn(
    const float* __restrict__ qkv, float* __restrict__ ao)
{
    __shared__ float Qs[QBLK][96];
    __shared__ float Ks[TBLK][100];
    __shared__ float Vs[TBLK][96];
    __shared__ float Ps[QBLK][65];
    __shared__ float scl[QBLK];
    __shared__ float ll[QBLK];

    int tid = threadIdx.x;
    int row0 = blockIdx.x * QBLK;
    int h = blockIdx.y;
    const float scale = 0.1020620726f;   // 1/sqrt(96)

    for (int f = tid; f < QBLK * 24; f += 256) {
        int r = f / 24, c = f % 24;
        *(float4*)&Qs[r][c * 4] =
            *(const float4*)(qkv + (size_t)(row0 + r) * 1152 + h * 96 + c * 4);
    }

    int t = tid & 63;
    int w = tid >> 6;
    int pr = w + 4 * ((tid & 63) >> 4);
    int ds = (tid & 15) * 6;

    float m[4], lsum[4], o[6];
    #pragma unroll
    for (int k = 0; k < 4; k++) { m[k] = -1e30f; lsum[k] = 0.f; }
    #pragma unroll
    for (int i = 0; i < 6; i++) o[i] = 0.f;

    for (int tile = 0; tile < N_TOK / TBLK; ++tile) {
        int t0 = tile * TBLK;
        __syncthreads();
        for (int f = tid; f < TBLK * 24; f += 256) {
            int r = f / 24, c = f % 24;
            const float* src = qkv + (size_t)(t0 + r) * 1152 + 384 + h * 96 + c * 4;
            *(float4*)&Ks[r][c * 4] = *(const float4*)src;
            *(float4*)&Vs[r][c * 4] = *(const float4*)(src + 384);
        }
        __syncthreads();

        float s[4] = {0.f, 0.f, 0.f, 0.f};
        #pragma unroll
        for (int d4 = 0; d4 < 24; ++d4) {
            float4 kv = *(const float4*)&Ks[t][d4 * 4];
            #pragma unroll
            for (int k = 0; k < 4; ++k) {
                float4 qv = *(const float4*)&Qs[w + 4 * k][d4 * 4];
                s[k] += qv.x * kv.x + qv.y * kv.y + qv.z * kv.z + qv.w * kv.w;
            }
        }
        #pragma unroll
        for (int k = 0; k < 4; ++k) {
            float sv = s[k] * scale;
            float tmax = sv;
            #pragma unroll
            for (int off = 32; off > 0; off >>= 1)
                tmax = fmaxf(tmax, __shfl_xor(tmax, off));
            float mnew = fmaxf(m[k], tmax);
            float p = __expf(sv - mnew);
            float ts = p;
            #pragma unroll
            for (int off = 32; off > 0; off >>= 1)
                ts += __shfl_xor(ts, off);
            float sc = __expf(m[k] - mnew);
            lsum[k] = lsum[k] * sc + ts;
            m[k] = mnew;
            Ps[w + 4 * k][t] = p;
            if (t == 0) scl[w + 4 * k] = sc;
        }
        float sc_mine = scl[pr];
        #pragma unroll
        for (int i = 0; i < 6; i++) o[i] *= sc_mine;
        for (int tt = 0; tt < TBLK; ++tt) {
            float p = Ps[pr][tt];
            float2 v0 = *(const float2*)&Vs[tt][ds + 0];
            float2 v1 = *(const float2*)&Vs[tt][ds + 2];
            float2 v2 = *(const float2*)&Vs[tt][ds + 4];
            o[0] += p * v0.x; o[1] += p * v0.y;
            o[2] += p * v1.x; o[3] += p * v1.y;
            o[4] += p * v2.x; o[5] += p * v2.y;
        }
    }
    #pragma unroll
    for (int k = 0; k < 4; ++k)
        if (t == 0) ll[w + 4 * k] = lsum[k];
    float inv = 1.f / ll[pr];
    float* dst = ao + (size_t)(row0 + pr) * C_S + h * 96 + ds;
    float2 r0, r1, r2;
    r0.x = o[0] * inv; r0.y = o[1] * inv;
    r1.x = o[2] * inv; r1.y = o[3] * inv;
    r2.x = o[4] * inv; r2.y = o[5] * inv;
    *(float2*)(dst + 0) = r0;
    *(float2*)(dst + 2) = r1;
    *(float2*)(dst + 4) = r2;
}

// ---------------------------------------------------------------------------
__global__ __launch_bounds__(64) void k_tokout(
    const float* __restrict__ tf, const float* __restrict__ co_w,
    const float* __restrict__ co_b, float* __restrict__ tout)
{
    int t = blockIdx.x, lane = threadIdx.x;
    float a0 = 0.f, a1 = 0.f, a2 = 0.f;
    for (int c = lane; c < C_S; c += 64) {
        float v = tf[(size_t)t * C_S + c];
        a0 += v * co_w[c];
        a1 += v * co_w[C_S + c];
        a2 += v * co_w[2 * C_S + c];
    }
    #pragma unroll
    for (int off = 32; off > 0; off >>= 1) {
        a0 += __shfl_down(a0, off);
        a1 += __shfl_down(a1, off);
        a2 += __shfl_down(a2, off);
    }
    if (lane == 0) {
        tout[t * 3 + 0] = a0 + co_b[0];
        tout[t * 3 + 1] = a1 + co_b[1];
        tout[t * 3 + 2] = a2 + co_b[2];
    }
}

__global__ __launch_bounds__(256) void k_gather(
    const float* __restrict__ tout, const int* __restrict__ idx,
    float* __restrict__ out)
{
    int e = blockIdx.x * 256 + threadIdx.x;
    if (e < N_ATOM * 3) {
        int a = e / 3, j = e - a * 3;
        out[e] = tout[idx[a] * 3 + j];
    }
}

// ---------------------------------------------------------------------------
extern "C" void kernel_launch(void* const* d_in, const int* in_sizes, int n_in,
                              void* d_out, int out_size, void* d_ws, size_t ws_size,
                              hipStream_t stream)
{
    const float* x_noisy   = (const float*)d_in[0];
    const float* s         = (const float*)d_in[1];
    // d_in[2] = z : dead code in the reference (z_cond unused) -> never read
    const float* sigma     = (const float*)d_in[3];
    const int*   a2t       = (const int*)d_in[4];
    const float* fourier_w = (const float*)d_in[5];
    const float* fourier_b = (const float*)d_in[6];
    const float* ns_w      = (const float*)d_in[7];
    const float* ns_b      = (const float*)d_in[8];
    const float* lns_g     = (const float*)d_in[11];
    const float* lns_b     = (const float*)d_in[12];
    const float* ce_w      = (const float*)d_in[15];
    const float* ce_b      = (const float*)d_in[16];
    const float* in_w      = (const float*)d_in[17];
    const float* in_b      = (const float*)d_in[18];
    const float* out_w     = (const float*)d_in[19];
    const float* out_b     = (const float*)d_in[20];
    const float* ffln_g    = (const float*)d_in[21];
    const float* ffln_b    = (const float*)d_in[22];
    const float* ff1_w     = (const float*)d_in[23];
    const float* ff1_b     = (const float*)d_in[24];
    const float* ff2_w     = (const float*)d_in[25];
    const float* ff2_b     = (const float*)d_in[26];
    const float* co_w      = (const float*)d_in[27];
    const float* co_b      = (const float*)d_in[28];

    float* ws  = (float*)d_ws;
    float* out = (float*)d_out;

    hipLaunchKernelGGL(k_setup, dim3(1), dim3(384), 0, stream,
                       sigma, fourier_w, fourier_b, ns_w, ns_b,
                       ws + OFF_NOISE, ws + OFF_NSPROJ, ws + OFF_SEGX);
    hipLaunchKernelGGL(k_segsum, dim3((N_ATOM + 255) / 256), dim3(256), 0, stream,
                       x_noisy, a2t, ws + OFF_SEGX);
    hipLaunchKernelGGL(k_tokenfeat, dim3(N_TOK), dim3(128), 0, stream,
                       s, ws + OFF_SEGX, ws + OFF_NSPROJ, lns_g, lns_b,
                       ce_w, ce_b, ws + OFF_TF1);
    // qkv = tf1 @ in_w^T + in_b    [1024,1152]
    hipLaunchKernelGGL((k_gemm<0, false>), dim3(1152 / 64, 1024 / 64), dim3(256), 0, stream,
                       ws + OFF_TF1, in_w, in_b, nullptr, ws + OFF_QKV, 1024, 1152, 384);
    // attention
    hipLaunchKernelGGL(k_attn, dim3(N_TOK / QBLK, NH), dim3(256), 0, stream,
                       ws + OFF_QKV, ws + OFF_AO);
    // tf2 = tf1 + ao @ out_w^T + out_b
    hipLaunchKernelGGL((k_gemm<0, true>), dim3(384 / 64, 1024 / 64), dim3(256), 0, stream,
                       ws + OFF_AO, out_w, out_b, ws + OFF_TF1, ws + OFF_TF2, 1024, 384, 384);
    // lnh = LN(tf2)
    hipLaunchKernelGGL(k_ln, dim3(N_TOK), dim3(128), 0, stream,
                       ws + OFF_TF2, ffln_g, ffln_b, ws + OFF_LNH);
    // h1 = silu(lnh @ ff1_w^T + ff1_b)   [1024,1536]
    hipLaunchKernelGGL((k_gemm<1, false>), dim3(1536 / 64, 1024 / 64), dim3(256), 0, stream,
                       ws + OFF_LNH, ff1_w, ff1_b, nullptr, ws + OFF_H1, 1024, 1536, 384);
    // tf3 = tf2 + h1 @ ff2_w^T + ff2_b
    hipLaunchKernelGGL((k_gemm<0, true>), dim3(384 / 64, 1024 / 64), dim3(256), 0, stream,
                       ws + OFF_H1, ff2_w, ff2_b, ws + OFF_TF2, ws + OFF_TF3, 1024, 384, 1536);
    // token head + gather
    hipLaunchKernelGGL(k_tokout, dim3(N_TOK), dim3(64), 0, stream,
                       ws + OFF_TF3, co_w, co_b, ws + OFF_TOUT);
    hipLaunchKernelGGL(k_gather, dim3((N_ATOM * 3 + 255) / 256), dim3(256), 0, stream,
                       ws + OFF_TOUT, a2t, out);
}

// Round 4
// 179.723 us; speedup vs baseline: 3.0548x; 1.2557x over previous
//
#include <hip/hip_runtime.h>
#include <hip/hip_bf16.h>
#include <math.h>

#define N_TOK 1024
#define N_ATOM 24576
#define C_S 384
#define FDIM 256
#define NH 4
#define HD 96

typedef __attribute__((ext_vector_type(8))) short short8;   // 8 bf16 (4 VGPR)
typedef __attribute__((ext_vector_type(4))) float f32x4;

// ---- workspace layout (float-slot offsets, all 16B-aligned) ----
#define OFF_SEGX   0u          // 4096
#define OFF_NOISE  4096u       // 256
#define OFF_NSPROJ 4352u       // 384
#define OFF_TF1    4736u       // 393216 f32
#define OFF_QKV    397952u     // 1179648 f32
#define OFF_TF2    1577600u    // 393216 f32
#define OFF_TF3    1970816u    // 393216 f32
#define OFF_TF1B   2364032u    // 393216 bf16 (196608 slots)
#define OFF_AOB    2560640u    // 393216 bf16
#define OFF_LNHB   2757248u    // 393216 bf16
#define OFF_H1B    2953856u    // 786432 bf16 (393216 slots)
#define OFF_WINB   3347072u    // 442368 bf16 (221184 slots)
#define OFF_WOUTB  3568256u    // 147456 bf16 (73728 slots)
#define OFF_WF1B   3641984u    // 589824 bf16 (294912 slots)
#define OFF_WF2B   3936896u    // 589824 bf16 (294912 slots)

__device__ inline __hip_bfloat16 f2bf(float x) { return __float2bfloat16(x); }
union BFPack { short8 v; __hip_bfloat16 h[8]; };
__device__ inline short8 pack8(float4 a, float4 b)
{
    BFPack p;
    p.h[0] = f2bf(a.x); p.h[1] = f2bf(a.y); p.h[2] = f2bf(a.z); p.h[3] = f2bf(a.w);
    p.h[4] = f2bf(b.x); p.h[5] = f2bf(b.y); p.h[6] = f2bf(b.z); p.h[7] = f2bf(b.w);
    return p.v;
}

// ---------------------------------------------------------------------------
// weights -> bf16 (once per launch), block 0 also zeroes segx
__global__ __launch_bounds__(256) void k_cvtw(
    const float* __restrict__ in_w, const float* __restrict__ out_w,
    const float* __restrict__ ff1_w, const float* __restrict__ ff2_w,
    __hip_bfloat16* __restrict__ winb, __hip_bfloat16* __restrict__ woutb,
    __hip_bfloat16* __restrict__ wf1b, __hip_bfloat16* __restrict__ wf2b,
    float* __restrict__ segx)
{
    int tid = threadIdx.x;
    if (blockIdx.x == 0) {
        #pragma unroll
        for (int j = 0; j < 16; ++j) segx[tid * 16 + j] = 0.f;
    }
    size_t e8 = (size_t)blockIdx.x * 256 + tid;   // index in units of 8 elems
    const float* src; __hip_bfloat16* dst; size_t off;
    if (e8 < 55296)       { src = in_w;  dst = winb;  off = e8; }
    else if (e8 < 73728)  { src = out_w; dst = woutb; off = e8 - 55296; }
    else if (e8 < 147456) { src = ff1_w; dst = wf1b;  off = e8 - 73728; }
    else                  { src = ff2_w; dst = wf2b;  off = e8 - 147456; }
    float4 a = *(const float4*)(src + off * 8);
    float4 b = *(const float4*)(src + off * 8 + 4);
    *(short8*)(dst + off * 8) = pack8(a, b);
}

// ---------------------------------------------------------------------------
// setup: fourier embedding -> noise [256] -> ns_proj [384]
__global__ __launch_bounds__(384) void k_setup(
    const float* __restrict__ sigma,
    const float* __restrict__ fw, const float* __restrict__ fb,
    const float* __restrict__ nsw, const float* __restrict__ nsb,
    float* __restrict__ noise_out, float* __restrict__ nsproj_out)
{
    __shared__ float emb[256];
    __shared__ float noise[256];
    int tid = threadIdx.x;
    float sg = sigma[0];
    if (tid < 128) {
        float fr = expf(-logf(1000.f) * (float)tid / 128.f);
        float x = sg * fr;
        emb[tid]       = cosf(x);
        emb[tid + 128] = sinf(x);
    }
    __syncthreads();
    if (tid < 256) {
        const float* wr = fw + (size_t)tid * 256;
        float acc = fb[tid];
        for (int i = 0; i < 256; i++) acc += emb[i] * wr[i];
        noise[tid] = acc;
        noise_out[tid] = acc;
    }
    __syncthreads();
    if (tid < 384) {
        const float* wr = nsw + (size_t)tid * 256;
        float acc = nsb[tid];
        for (int i = 0; i < 256; i++) acc += noise[i] * wr[i];
        nsproj_out[tid] = acc;
    }
}

// ---------------------------------------------------------------------------
__global__ __launch_bounds__(256) void k_segsum(
    const float* __restrict__ x, const int* __restrict__ idx,
    float* __restrict__ segx)
{
    int a = blockIdx.x * 256 + threadIdx.x;
    if (a < N_ATOM) {
        int t = idx[a];
        atomicAdd(&segx[t * 4 + 0], x[a * 3 + 0]);
        atomicAdd(&segx[t * 4 + 1], x[a * 3 + 1]);
        atomicAdd(&segx[t * 4 + 2], x[a * 3 + 2]);
        atomicAdd(&segx[t * 4 + 3], 1.f);
    }
}

// ---------------------------------------------------------------------------
__device__ inline float blockReduceSum128(float v, volatile float* sm)
{
    #pragma unroll
    for (int off = 32; off > 0; off >>= 1) v += __shfl_down(v, off);
    if ((threadIdx.x & 63) == 0) sm[threadIdx.x >> 6] = v;
    __syncthreads();
    float r = sm[0] + sm[1];
    __syncthreads();
    return r;
}

// token_feat = LN(s)*g+b + ns_proj + (cnt>0 ? mean_x@ce_w.T + ce_b : 0)
// writes f32 (residual) + bf16 (GEMM A)
__global__ __launch_bounds__(128) void k_tokenfeat(
    const float* __restrict__ s, const float* __restrict__ segx,
    const float* __restrict__ nsproj,
    const float* __restrict__ g, const float* __restrict__ b,
    const float* __restrict__ ce_w, const float* __restrict__ ce_b,
    float* __restrict__ tf, __hip_bfloat16* __restrict__ tfb)
{
    __shared__ float sm[2];
    int t = blockIdx.x, tid = threadIdx.x;
    const float* sr = s + (size_t)t * C_S;
    float x0 = sr[tid], x1 = sr[tid + 128], x2 = sr[tid + 256];
    float total = blockReduceSum128(x0 + x1 + x2, sm);
    float mean = total * (1.f / 384.f);
    float d0 = x0 - mean, d1 = x1 - mean, d2 = x2 - mean;
    float vtot = blockReduceSum128(d0 * d0 + d1 * d1 + d2 * d2, sm);
    float inv = rsqrtf(vtot * (1.f / 384.f) + 1e-5f);
    float cnt = segx[t * 4 + 3];
    float mx0 = 0.f, mx1 = 0.f, mx2 = 0.f;
    int has = cnt > 0.f;
    if (has) {
        float ic = 1.f / cnt;
        mx0 = segx[t * 4 + 0] * ic;
        mx1 = segx[t * 4 + 1] * ic;
        mx2 = segx[t * 4 + 2] * ic;
    }
    float xs[3] = {d0, d1, d2};
    #pragma unroll
    for (int l = 0; l < 3; l++) {
        int c = tid + l * 128;
        float ln = xs[l] * inv * g[c] + b[c];
        float coord = 0.f;
        if (has)
            coord = mx0 * ce_w[c * 3 + 0] + mx1 * ce_w[c * 3 + 1]
                  + mx2 * ce_w[c * 3 + 2] + ce_b[c];
        float v = ln + nsproj[c] + coord;
        tf[(size_t)t * C_S + c] = v;
        tfb[(size_t)t * C_S + c] = f2bf(v);
    }
}

// plain LN (for ffln), bf16 out
__global__ __launch_bounds__(128) void k_ln(
    const float* __restrict__ in, const float* __restrict__ g,
    const float* __restrict__ b, __hip_bfloat16* __restrict__ out)
{
    __shared__ float sm[2];
    int t = blockIdx.x, tid = threadIdx.x;
    const float* sr = in + (size_t)t * C_S;
    float x0 = sr[tid], x1 = sr[tid + 128], x2 = sr[tid + 256];
    float total = blockReduceSum128(x0 + x1 + x2, sm);
    float mean = total * (1.f / 384.f);
    float d0 = x0 - mean, d1 = x1 - mean, d2 = x2 - mean;
    float vtot = blockReduceSum128(d0 * d0 + d1 * d1 + d2 * d2, sm);
    float inv = rsqrtf(vtot * (1.f / 384.f) + 1e-5f);
    float xs[3] = {d0, d1, d2};
    #pragma unroll
    for (int l = 0; l < 3; l++) {
        int c = tid + l * 128;
        out[(size_t)t * C_S + c] = f2bf(xs[l] * inv * g[c] + b[c]);
    }
}

// ---------------------------------------------------------------------------
// bf16-in MFMA GEMM: C = act(A[M,K] @ W[N,K]^T + bias) (+ res).
// 64x64 tile, BK=64, 4 waves x 32x32 out. OB: bf16 output.
template <int ACT, bool RES, bool OB>
__global__ __launch_bounds__(256) void k_gemm(
    const __hip_bfloat16* __restrict__ A, const __hip_bfloat16* __restrict__ W,
    const float* __restrict__ bias, const float* __restrict__ res,
    float* __restrict__ Cf, __hip_bfloat16* __restrict__ Cb,
    int M, int N, int K)
{
    __shared__ __hip_bfloat16 As[64][72];   // 144B rows -> uniform bank spread
    __shared__ __hip_bfloat16 Bs[64][72];

    int tid = threadIdx.x;
    int bm = blockIdx.y * 64, bn = blockIdx.x * 64;
    int w = tid >> 6, lane = tid & 63;
    int wr = (w >> 1) * 32, wc = (w & 1) * 32;
    int fr = lane & 15, kg = lane >> 4;

    int sr = tid >> 2;            // staging row 0..63
    int sc = (tid & 3) << 4;      // staging col 0,16,32,48 (bf16)

    f32x4 acc[2][2] = {};

    for (int k0 = 0; k0 < K; k0 += 64) {
        const __hip_bfloat16* ag = A + (size_t)(bm + sr) * K + k0 + sc;
        const __hip_bfloat16* wg = W + (size_t)(bn + sr) * K + k0 + sc;
        short8 a0 = *(const short8*)(ag + 0);
        short8 a1 = *(const short8*)(ag + 8);
        short8 b0 = *(const short8*)(wg + 0);
        short8 b1 = *(const short8*)(wg + 8);
        __syncthreads();
        *(short8*)&As[sr][sc + 0] = a0;
        *(short8*)&As[sr][sc + 8] = a1;
        *(short8*)&Bs[sr][sc + 0] = b0;
        *(short8*)&Bs[sr][sc + 8] = b1;
        __syncthreads();

        short8 af[2][2], bf[2][2];
        #pragma unroll
        for (int i = 0; i < 2; ++i)
            #pragma unroll
            for (int kh = 0; kh < 2; ++kh) {
                af[i][kh] = *(const short8*)&As[wr + i * 16 + fr][kh * 32 + kg * 8];
                bf[i][kh] = *(const short8*)&Bs[wc + i * 16 + fr][kh * 32 + kg * 8];
            }
        #pragma unroll
        for (int kh = 0; kh < 2; ++kh)
            #pragma unroll
            for (int i = 0; i < 2; ++i)
                #pragma unroll
                for (int j = 0; j < 2; ++j)
                    acc[i][j] = __builtin_amdgcn_mfma_f32_16x16x32_bf16(
                        af[i][kh], bf[j][kh], acc[i][j], 0, 0, 0);
    }

    // epilogue: C/D layout col=lane&15, row=(lane>>4)*4+reg
    #pragma unroll
    for (int i = 0; i < 2; ++i) {
        #pragma unroll
        for (int j = 0; j < 2; ++j) {
            int n = bn + wc + j * 16 + fr;
            float bv = bias[n];
            #pragma unroll
            for (int r = 0; r < 4; ++r) {
                int m = bm + wr + i * 16 + kg * 4 + r;
                float v = acc[i][j][r] + bv;
                if (ACT == 1) v = v / (1.f + __expf(-v));   // silu
                if (RES) v += res[(size_t)m * N + n];
                if (OB) Cb[(size_t)m * N + n] = f2bf(v);
                else    Cf[(size_t)m * N + n] = v;
            }
        }
    }
}

// ---------------------------------------------------------------------------
// flash attention (f32): block = (8 Q-rows, head), 512 blocks -> 2 blocks/CU.
// PV split across lane halves; ao written in bf16.
#define QBLK 8
#define TBLK 64

__global__ __launch_bounds__(256) void k_attn(
    const float* __restrict__ qkv, __hip_bfloat16* __restrict__ ao)
{
    __shared__ float Qs[QBLK][96];
    __shared__ float Ks[TBLK][100];      // pad: slot=(t+d4)%8 uniform
    __shared__ float Vs[TBLK][96];
    __shared__ float Ps[QBLK][65];
    __shared__ float scl[QBLK];
    __shared__ float ll[QBLK];

    int tid = threadIdx.x;
    int row0 = blockIdx.x * QBLK;
    int h = blockIdx.y;
    const float scale = 0.1020620726f;   // 1/sqrt(96)

    for (int f = tid; f < QBLK * 24; f += 256) {
        int r = f / 24, c = f % 24;
        *(float4*)&Qs[r][c * 4] =
            *(const float4*)(qkv + (size_t)(row0 + r) * 1152 + h * 96 + c * 4);
    }

    int t = tid & 63;                    // score column within tile
    int w = tid >> 6;                    // wave id: owns rows w, w+4
    int pr = w + 4 * ((tid >> 4) & 1);   // PV row
    int hf = (tid >> 5) & 1;             // PV tt-half
    int ds = (tid & 15) * 6;             // PV d-slice: 6 floats

    float m[2], lsum[2], o[6];
    #pragma unroll
    for (int k = 0; k < 2; k++) { m[k] = -1e30f; lsum[k] = 0.f; }
    #pragma unroll
    for (int i = 0; i < 6; i++) o[i] = 0.f;

    for (int tile = 0; tile < N_TOK / TBLK; ++tile) {
        int t0 = tile * TBLK;
        __syncthreads();                 // LDS reuse fence (covers Q 1st iter)
        for (int f = tid; f < TBLK * 24; f += 256) {
            int r = f / 24, c = f % 24;
            const float* src = qkv + (size_t)(t0 + r) * 1152 + 384 + h * 96 + c * 4;
            *(float4*)&Ks[r][c * 4] = *(const float4*)src;
            *(float4*)&Vs[r][c * 4] = *(const float4*)(src + 384);
        }
        __syncthreads();

        // ---- scores: s[k] = Q[w+4k] . K[t] ----
        float s[2] = {0.f, 0.f};
        #pragma unroll
        for (int d4 = 0; d4 < 24; ++d4) {
            float4 kv = *(const float4*)&Ks[t][d4 * 4];
            #pragma unroll
            for (int k = 0; k < 2; ++k) {
                float4 qv = *(const float4*)&Qs[w + 4 * k][d4 * 4];
                s[k] += qv.x * kv.x + qv.y * kv.y + qv.z * kv.z + qv.w * kv.w;
            }
        }
        // ---- online softmax update (per wave-owned row) ----
        #pragma unroll
        for (int k = 0; k < 2; ++k) {
            float sv = s[k] * scale;
            float tmax = sv;
            #pragma unroll
            for (int off = 32; off > 0; off >>= 1)
                tmax = fmaxf(tmax, __shfl_xor(tmax, off));
            float mnew = fmaxf(m[k], tmax);
            float p = __expf(sv - mnew);
            float ts = p;
            #pragma unroll
            for (int off = 32; off > 0; off >>= 1)
                ts += __shfl_xor(ts, off);
            float sc = __expf(m[k] - mnew);
            lsum[k] = lsum[k] * sc + ts;
            m[k] = mnew;
            Ps[w + 4 * k][t] = p;
            if (t == 0) scl[w + 4 * k] = sc;
        }
        // ---- PV (wave-local LDS handoff): lane-half splits tt range ----
        float sc_mine = scl[pr];
        #pragma unroll
        for (int i = 0; i < 6; i++) o[i] *= sc_mine;
        int tb = hf * 32;
        #pragma unroll 8
        for (int tt = tb; tt < tb + 32; ++tt) {
            float p = Ps[pr][tt];
            float2 v0 = *(const float2*)&Vs[tt][ds + 0];
            float2 v1 = *(const float2*)&Vs[tt][ds + 2];
            float2 v2 = *(const float2*)&Vs[tt][ds + 4];
            o[0] += p * v0.x; o[1] += p * v0.y;
            o[2] += p * v1.x; o[3] += p * v1.y;
            o[4] += p * v2.x; o[5] += p * v2.y;
        }
    }
    #pragma unroll
    for (int k = 0; k < 2; ++k)
        if (t == 0) ll[w + 4 * k] = lsum[k];
    // combine tt-halves (lane L <-> L^32 hold same (pr,ds))
    #pragma unroll
    for (int i = 0; i < 6; i++) o[i] += __shfl_xor(o[i], 32);
    if (hf == 0) {
        float inv = 1.f / ll[pr];
        __hip_bfloat16* dst = ao + (size_t)(row0 + pr) * C_S + h * 96 + ds;
        #pragma unroll
        for (int i = 0; i < 6; i++) dst[i] = f2bf(o[i] * inv);
    }
}

// ---------------------------------------------------------------------------
// fused token head + gather: out[a] = tf3[idx[a]] . co_w^T + co_b  (wave/atom)
__global__ __launch_bounds__(256) void k_atomout(
    const float* __restrict__ tf, const int* __restrict__ idx,
    const float* __restrict__ co_w, const float* __restrict__ co_b,
    float* __restrict__ out)
{
    int a = blockIdx.x * 4 + (threadIdx.x >> 6);
    int lane = threadIdx.x & 63;
    if (a >= N_ATOM) return;
    const float* base = tf + (size_t)idx[a] * C_S;
    float a0 = 0.f, a1 = 0.f, a2 = 0.f;
    #pragma unroll
    for (int i = 0; i < 6; ++i) {
        int c = lane + i * 64;
        float v = base[c];
        a0 += v * co_w[c];
        a1 += v * co_w[C_S + c];
        a2 += v * co_w[2 * C_S + c];
    }
    #pragma unroll
    for (int off = 32; off > 0; off >>= 1) {
        a0 += __shfl_down(a0, off);
        a1 += __shfl_down(a1, off);
        a2 += __shfl_down(a2, off);
    }
    if (lane == 0) {
        out[a * 3 + 0] = a0 + co_b[0];
        out[a * 3 + 1] = a1 + co_b[1];
        out[a * 3 + 2] = a2 + co_b[2];
    }
}

// ---------------------------------------------------------------------------
extern "C" void kernel_launch(void* const* d_in, const int* in_sizes, int n_in,
                              void* d_out, int out_size, void* d_ws, size_t ws_size,
                              hipStream_t stream)
{
    const float* x_noisy   = (const float*)d_in[0];
    const float* s         = (const float*)d_in[1];
    // d_in[2] = z : dead code in the reference (z_cond unused) -> never read
    const float* sigma     = (const float*)d_in[3];
    const int*   a2t       = (const int*)d_in[4];
    const float* fourier_w = (const float*)d_in[5];
    const float* fourier_b = (const float*)d_in[6];
    const float* ns_w      = (const float*)d_in[7];
    const float* ns_b      = (const float*)d_in[8];
    const float* lns_g     = (const float*)d_in[11];
    const float* lns_b     = (const float*)d_in[12];
    const float* ce_w      = (const float*)d_in[15];
    const float* ce_b      = (const float*)d_in[16];
    const float* in_w      = (const float*)d_in[17];
    const float* in_b      = (const float*)d_in[18];
    const float* out_w     = (const float*)d_in[19];
    const float* out_b     = (const float*)d_in[20];
    const float* ffln_g    = (const float*)d_in[21];
    const float* ffln_b    = (const float*)d_in[22];
    const float* ff1_w     = (const float*)d_in[23];
    const float* ff1_b     = (const float*)d_in[24];
    const float* ff2_w     = (const float*)d_in[25];
    const float* ff2_b     = (const float*)d_in[26];
    const float* co_w      = (const float*)d_in[27];
    const float* co_b      = (const float*)d_in[28];

    float* ws  = (float*)d_ws;
    float* out = (float*)d_out;
    __hip_bfloat16* tf1b  = (__hip_bfloat16*)(ws + OFF_TF1B);
    __hip_bfloat16* aob   = (__hip_bfloat16*)(ws + OFF_AOB);
    __hip_bfloat16* lnhb  = (__hip_bfloat16*)(ws + OFF_LNHB);
    __hip_bfloat16* h1b   = (__hip_bfloat16*)(ws + OFF_H1B);
    __hip_bfloat16* winb  = (__hip_bfloat16*)(ws + OFF_WINB);
    __hip_bfloat16* woutb = (__hip_bfloat16*)(ws + OFF_WOUTB);
    __hip_bfloat16* wf1b  = (__hip_bfloat16*)(ws + OFF_WF1B);
    __hip_bfloat16* wf2b  = (__hip_bfloat16*)(ws + OFF_WF2B);

    // weights -> bf16 (+ zero segx in block 0)
    hipLaunchKernelGGL(k_cvtw, dim3(864), dim3(256), 0, stream,
                       in_w, out_w, ff1_w, ff2_w, winb, woutb, wf1b, wf2b,
                       ws + OFF_SEGX);
    hipLaunchKernelGGL(k_segsum, dim3(96), dim3(256), 0, stream,
                       x_noisy, a2t, ws + OFF_SEGX);
    hipLaunchKernelGGL(k_setup, dim3(1), dim3(384), 0, stream,
                       sigma, fourier_w, fourier_b, ns_w, ns_b,
                       ws + OFF_NOISE, ws + OFF_NSPROJ);
    hipLaunchKernelGGL(k_tokenfeat, dim3(N_TOK), dim3(128), 0, stream,
                       s, ws + OFF_SEGX, ws + OFF_NSPROJ, lns_g, lns_b,
                       ce_w, ce_b, ws + OFF_TF1, tf1b);
    // qkv = tf1 @ in_w^T + in_b    [1024,1152] f32
    hipLaunchKernelGGL((k_gemm<0, false, false>), dim3(18, 16), dim3(256), 0, stream,
                       tf1b, winb, in_b, nullptr, ws + OFF_QKV, (__hip_bfloat16*)nullptr,
                       1024, 1152, 384);
    // attention -> ao bf16
    hipLaunchKernelGGL(k_attn, dim3(N_TOK / QBLK, NH), dim3(256), 0, stream,
                       ws + OFF_QKV, aob);
    // tf2 = tf1 + ao @ out_w^T + out_b  (f32)
    hipLaunchKernelGGL((k_gemm<0, true, false>), dim3(6, 16), dim3(256), 0, stream,
                       aob, woutb, out_b, ws + OFF_TF1, ws + OFF_TF2,
                       (__hip_bfloat16*)nullptr, 1024, 384, 384);
    // lnh = LN(tf2) -> bf16
    hipLaunchKernelGGL(k_ln, dim3(N_TOK), dim3(128), 0, stream,
                       ws + OFF_TF2, ffln_g, ffln_b, lnhb);
    // h1 = silu(lnh @ ff1_w^T + ff1_b) -> bf16
    hipLaunchKernelGGL((k_gemm<1, false, true>), dim3(24, 16), dim3(256), 0, stream,
                       lnhb, wf1b, ff1_b, nullptr, (float*)nullptr, h1b,
                       1024, 1536, 384);
    // tf3 = tf2 + h1 @ ff2_w^T + ff2_b  (f32)
    hipLaunchKernelGGL((k_gemm<0, true, false>), dim3(6, 16), dim3(256), 0, stream,
                       h1b, wf2b, ff2_b, ws + OFF_TF2, ws + OFF_TF3,
                       (__hip_bfloat16*)nullptr, 1024, 384, 1536);
    // fused token head + gather
    hipLaunchKernelGGL(k_atomout, dim3(N_ATOM / 4, 1), dim3(256), 0, stream,
                       ws + OFF_TF3, a2t, co_w, co_b, out);
}

// Round 5
// 135.998 us; speedup vs baseline: 4.0369x; 1.3215x over previous
//
#include <hip/hip_runtime.h>
#include <hip/hip_bf16.h>
#include <math.h>

#define N_TOK 1024
#define N_ATOM 24576
#define C_S 384
#define FDIM 256
#define NH 4
#define HD 96

typedef __attribute__((ext_vector_type(8))) short short8;   // 8 bf16 (4 VGPR)
typedef __attribute__((ext_vector_type(4))) float f32x4;

// ---- workspace layout (float-slot offsets, all 16B-aligned) ----
#define OFF_SEGX   0u          // 4096
#define OFF_NSPROJ 4352u       // 384
#define OFF_TF1    4736u       // 393216 f32
#define OFF_QKV    397952u     // qkv bf16 [1024][1152] (589824 slots used)
#define OFF_TF2    1577600u    // 393216 f32
#define OFF_TF3    1970816u    // 393216 f32
#define OFF_TF1B   2364032u    // tf1 bf16 (196608 slots)
#define OFF_AOB    2560640u    // ao bf16
#define OFF_LNHB   2757248u    // lnh bf16
#define OFF_H1B    2953856u    // h1 bf16 (393216 slots)
#define OFF_WINB   3347072u    // in_w bf16
#define OFF_WOUTB  3568256u    // out_w bf16
#define OFF_WF1B   3641984u    // ff1_w bf16
#define OFF_WF2B   3936896u    // ff2_w bf16

__device__ inline __hip_bfloat16 f2bf(float x) { return __float2bfloat16(x); }
union BFPack { short8 v; __hip_bfloat16 h[8]; };
__device__ inline short8 pack8(float4 a, float4 b)
{
    BFPack p;
    p.h[0] = f2bf(a.x); p.h[1] = f2bf(a.y); p.h[2] = f2bf(a.z); p.h[3] = f2bf(a.w);
    p.h[4] = f2bf(b.x); p.h[5] = f2bf(b.y); p.h[6] = f2bf(b.z); p.h[7] = f2bf(b.w);
    return p.v;
}

// ---------------------------------------------------------------------------
// blocks 0..863: weights -> bf16 (block 0 also zeroes segx)
// block 864: fourier embedding -> noise -> ns_proj
__global__ __launch_bounds__(256) void k_cvtw(
    const float* __restrict__ in_w, const float* __restrict__ out_w,
    const float* __restrict__ ff1_w, const float* __restrict__ ff2_w,
    __hip_bfloat16* __restrict__ winb, __hip_bfloat16* __restrict__ woutb,
    __hip_bfloat16* __restrict__ wf1b, __hip_bfloat16* __restrict__ wf2b,
    float* __restrict__ segx,
    const float* __restrict__ sigma,
    const float* __restrict__ fw, const float* __restrict__ fb,
    const float* __restrict__ nsw, const float* __restrict__ nsb,
    float* __restrict__ nsproj_out)
{
    __shared__ float emb[256];
    __shared__ float noise[256];
    int tid = threadIdx.x;

    if (blockIdx.x == 864) {           // ---- setup block ----
        float sg = sigma[0];
        if (tid < 128) {
            float fr = expf(-logf(1000.f) * (float)tid / 128.f);
            float x = sg * fr;
            emb[tid]       = cosf(x);
            emb[tid + 128] = sinf(x);
        }
        __syncthreads();
        {
            const float* wr = fw + (size_t)tid * 256;
            float acc = fb[tid];
            for (int i = 0; i < 256; i++) acc += emb[i] * wr[i];
            noise[tid] = acc;
        }
        __syncthreads();
        for (int o = tid; o < 384; o += 256) {
            const float* wr = nsw + (size_t)o * 256;
            float acc = nsb[o];
            for (int i = 0; i < 256; i++) acc += noise[i] * wr[i];
            nsproj_out[o] = acc;
        }
        return;
    }

    if (blockIdx.x == 0) {
        #pragma unroll
        for (int j = 0; j < 16; ++j) segx[tid * 16 + j] = 0.f;
    }
    size_t e8 = (size_t)blockIdx.x * 256 + tid;   // index in units of 8 elems
    const float* src; __hip_bfloat16* dst; size_t off;
    if (e8 < 55296)       { src = in_w;  dst = winb;  off = e8; }
    else if (e8 < 73728)  { src = out_w; dst = woutb; off = e8 - 55296; }
    else if (e8 < 147456) { src = ff1_w; dst = wf1b;  off = e8 - 73728; }
    else                  { src = ff2_w; dst = wf2b;  off = e8 - 147456; }
    float4 a = *(const float4*)(src + off * 8);
    float4 b = *(const float4*)(src + off * 8 + 4);
    *(short8*)(dst + off * 8) = pack8(a, b);
}

// ---------------------------------------------------------------------------
__global__ __launch_bounds__(256) void k_segsum(
    const float* __restrict__ x, const int* __restrict__ idx,
    float* __restrict__ segx)
{
    int a = blockIdx.x * 256 + threadIdx.x;
    if (a < N_ATOM) {
        int t = idx[a];
        atomicAdd(&segx[t * 4 + 0], x[a * 3 + 0]);
        atomicAdd(&segx[t * 4 + 1], x[a * 3 + 1]);
        atomicAdd(&segx[t * 4 + 2], x[a * 3 + 2]);
        atomicAdd(&segx[t * 4 + 3], 1.f);
    }
}

// ---------------------------------------------------------------------------
__device__ inline float blockReduceSum128(float v, volatile float* sm)
{
    #pragma unroll
    for (int off = 32; off > 0; off >>= 1) v += __shfl_down(v, off);
    if ((threadIdx.x & 63) == 0) sm[threadIdx.x >> 6] = v;
    __syncthreads();
    float r = sm[0] + sm[1];
    __syncthreads();
    return r;
}

// token_feat = LN(s)*g+b + ns_proj + (cnt>0 ? mean_x@ce_w.T + ce_b : 0)
__global__ __launch_bounds__(128) void k_tokenfeat(
    const float* __restrict__ s, const float* __restrict__ segx,
    const float* __restrict__ nsproj,
    const float* __restrict__ g, const float* __restrict__ b,
    const float* __restrict__ ce_w, const float* __restrict__ ce_b,
    float* __restrict__ tf, __hip_bfloat16* __restrict__ tfb)
{
    __shared__ float sm[2];
    int t = blockIdx.x, tid = threadIdx.x;
    const float* sr = s + (size_t)t * C_S;
    float x0 = sr[tid], x1 = sr[tid + 128], x2 = sr[tid + 256];
    float total = blockReduceSum128(x0 + x1 + x2, sm);
    float mean = total * (1.f / 384.f);
    float d0 = x0 - mean, d1 = x1 - mean, d2 = x2 - mean;
    float vtot = blockReduceSum128(d0 * d0 + d1 * d1 + d2 * d2, sm);
    float inv = rsqrtf(vtot * (1.f / 384.f) + 1e-5f);
    float cnt = segx[t * 4 + 3];
    float mx0 = 0.f, mx1 = 0.f, mx2 = 0.f;
    int has = cnt > 0.f;
    if (has) {
        float ic = 1.f / cnt;
        mx0 = segx[t * 4 + 0] * ic;
        mx1 = segx[t * 4 + 1] * ic;
        mx2 = segx[t * 4 + 2] * ic;
    }
    float xs[3] = {d0, d1, d2};
    #pragma unroll
    for (int l = 0; l < 3; l++) {
        int c = tid + l * 128;
        float ln = xs[l] * inv * g[c] + b[c];
        float coord = 0.f;
        if (has)
            coord = mx0 * ce_w[c * 3 + 0] + mx1 * ce_w[c * 3 + 1]
                  + mx2 * ce_w[c * 3 + 2] + ce_b[c];
        float v = ln + nsproj[c] + coord;
        tf[(size_t)t * C_S + c] = v;
        tfb[(size_t)t * C_S + c] = f2bf(v);
    }
}

// plain LN (for ffln), bf16 out
__global__ __launch_bounds__(128) void k_ln(
    const float* __restrict__ in, const float* __restrict__ g,
    const float* __restrict__ b, __hip_bfloat16* __restrict__ out)
{
    __shared__ float sm[2];
    int t = blockIdx.x, tid = threadIdx.x;
    const float* sr = in + (size_t)t * C_S;
    float x0 = sr[tid], x1 = sr[tid + 128], x2 = sr[tid + 256];
    float total = blockReduceSum128(x0 + x1 + x2, sm);
    float mean = total * (1.f / 384.f);
    float d0 = x0 - mean, d1 = x1 - mean, d2 = x2 - mean;
    float vtot = blockReduceSum128(d0 * d0 + d1 * d1 + d2 * d2, sm);
    float inv = rsqrtf(vtot * (1.f / 384.f) + 1e-5f);
    float xs[3] = {d0, d1, d2};
    #pragma unroll
    for (int l = 0; l < 3; l++) {
        int c = tid + l * 128;
        out[(size_t)t * C_S + c] = f2bf(xs[l] * inv * g[c] + b[c]);
    }
}

// ---------------------------------------------------------------------------
// bf16-in MFMA GEMM: C = act(A[M,K] @ W[N,K]^T + bias) (+ res). OB: bf16 out.
template <int ACT, bool RES, bool OB>
__global__ __launch_bounds__(256) void k_gemm(
    const __hip_bfloat16* __restrict__ A, const __hip_bfloat16* __restrict__ W,
    const float* __restrict__ bias, const float* __restrict__ res,
    float* __restrict__ Cf, __hip_bfloat16* __restrict__ Cb,
    int M, int N, int K)
{
    __shared__ __hip_bfloat16 As[64][72];
    __shared__ __hip_bfloat16 Bs[64][72];

    int tid = threadIdx.x;
    int bm = blockIdx.y * 64, bn = blockIdx.x * 64;
    int w = tid >> 6, lane = tid & 63;
    int wr = (w >> 1) * 32, wc = (w & 1) * 32;
    int fr = lane & 15, kg = lane >> 4;

    int sr = tid >> 2;
    int sc = (tid & 3) << 4;

    f32x4 acc[2][2] = {};

    for (int k0 = 0; k0 < K; k0 += 64) {
        const __hip_bfloat16* ag = A + (size_t)(bm + sr) * K + k0 + sc;
        const __hip_bfloat16* wg = W + (size_t)(bn + sr) * K + k0 + sc;
        short8 a0 = *(const short8*)(ag + 0);
        short8 a1 = *(const short8*)(ag + 8);
        short8 b0 = *(const short8*)(wg + 0);
        short8 b1 = *(const short8*)(wg + 8);
        __syncthreads();
        *(short8*)&As[sr][sc + 0] = a0;
        *(short8*)&As[sr][sc + 8] = a1;
        *(short8*)&Bs[sr][sc + 0] = b0;
        *(short8*)&Bs[sr][sc + 8] = b1;
        __syncthreads();

        short8 af[2][2], bf[2][2];
        #pragma unroll
        for (int i = 0; i < 2; ++i)
            #pragma unroll
            for (int kh = 0; kh < 2; ++kh) {
                af[i][kh] = *(const short8*)&As[wr + i * 16 + fr][kh * 32 + kg * 8];
                bf[i][kh] = *(const short8*)&Bs[wc + i * 16 + fr][kh * 32 + kg * 8];
            }
        #pragma unroll
        for (int kh = 0; kh < 2; ++kh)
            #pragma unroll
            for (int i = 0; i < 2; ++i)
                #pragma unroll
                for (int j = 0; j < 2; ++j)
                    acc[i][j] = __builtin_amdgcn_mfma_f32_16x16x32_bf16(
                        af[i][kh], bf[j][kh], acc[i][j], 0, 0, 0);
    }

    #pragma unroll
    for (int i = 0; i < 2; ++i) {
        #pragma unroll
        for (int j = 0; j < 2; ++j) {
            int n = bn + wc + j * 16 + fr;
            float bv = bias[n];
            #pragma unroll
            for (int r = 0; r < 4; ++r) {
                int m = bm + wr + i * 16 + kg * 4 + r;
                float v = acc[i][j][r] + bv;
                if (ACT == 1) v = v / (1.f + __expf(-v));   // silu
                if (RES) v += res[(size_t)m * N + n];
                if (OB) Cb[(size_t)m * N + n] = f2bf(v);
                else    Cf[(size_t)m * N + n] = v;
            }
        }
    }
}

// ---------------------------------------------------------------------------
// MFMA flash attention: block = (32 Q-rows, head), 4 waves, grid (32,4).
// S = Q.K^T via mfma(Qfrag, Kfrag); online softmax in C/D layout; PV via
// mfma(Pfrag, Vtfrag) with V stored transposed in LDS.
#define QB 32
#define TB 64

__global__ __launch_bounds__(256) void k_attn(
    const __hip_bfloat16* __restrict__ qkv, __hip_bfloat16* __restrict__ ao)
{
    __shared__ __hip_bfloat16 Ks[TB][104];   // K tile [t][d]
    __shared__ __hip_bfloat16 Vt[96][72];    // V^T tile [d][t]
    __shared__ __hip_bfloat16 Ps[QB][72];    // P [q][t]
    __shared__ float wmax[QB][4];            // per-wave row stats
    __shared__ float wsum[QB][4];

    int tid = threadIdx.x;
    int w = tid >> 6, l = tid & 63;
    int fr = l & 15, kg = l >> 4;
    int row0 = blockIdx.x * QB;
    int h = blockIdx.y;
    const float scale = 0.1020620726f;       // 1/sqrt(96)

    // Q fragments, held in registers: qf[qsub][dgrp]
    short8 qf[2][3];
    #pragma unroll
    for (int qs = 0; qs < 2; ++qs)
        #pragma unroll
        for (int dg = 0; dg < 3; ++dg)
            qf[qs][dg] = *(const short8*)(qkv
                + (size_t)(row0 + qs * 16 + fr) * 1152 + h * 96 + dg * 32 + kg * 8);

    float m[2][4], lsum[2][4];
    #pragma unroll
    for (int qs = 0; qs < 2; ++qs)
        #pragma unroll
        for (int r = 0; r < 4; ++r) { m[qs][r] = -1e30f; lsum[qs][r] = 0.f; }

    const int myqs = w >> 1;           // PV: wave's q-subtile
    const int d0 = (w & 1) * 48;       // PV: wave's 3 d-subtiles (0 or 48)
    f32x4 acc_o[3] = {};

    int st_t = tid >> 2, st_c = (tid & 3) * 24;     // K staging
    int vt_t = tid & 63, vt_d = (tid >> 6) * 24;    // V staging (transpose)

    for (int tile = 0; tile < N_TOK / TB; ++tile) {
        int t0 = tile * TB;
        __syncthreads();               // LDS reuse guard
        {   // stage K [t][d]
            const __hip_bfloat16* src =
                qkv + (size_t)(t0 + st_t) * 1152 + 384 + h * 96 + st_c;
            short8 k0 = *(const short8*)(src);
            short8 k1 = *(const short8*)(src + 8);
            short8 k2 = *(const short8*)(src + 16);
            *(short8*)&Ks[st_t][st_c + 0]  = k0;
            *(short8*)&Ks[st_t][st_c + 8]  = k1;
            *(short8*)&Ks[st_t][st_c + 16] = k2;
        }
        {   // stage V transposed [d][t]
            const __hip_bfloat16* src =
                qkv + (size_t)(t0 + vt_t) * 1152 + 768 + h * 96 + vt_d;
            BFPack p0, p1, p2;
            p0.v = *(const short8*)(src);
            p1.v = *(const short8*)(src + 8);
            p2.v = *(const short8*)(src + 16);
            #pragma unroll
            for (int j = 0; j < 8; ++j) {
                Vt[vt_d + j][vt_t]      = p0.h[j];
                Vt[vt_d + 8 + j][vt_t]  = p1.h[j];
                Vt[vt_d + 16 + j][vt_t] = p2.h[j];
            }
        }
        __syncthreads();

        // ---- S: rows = 32 q (both qsubs), cols = wave's 16-token slice ----
        f32x4 s[2] = {};
        #pragma unroll
        for (int dg = 0; dg < 3; ++dg) {
            short8 kf = *(const short8*)&Ks[w * 16 + fr][dg * 32 + kg * 8];
            s[0] = __builtin_amdgcn_mfma_f32_16x16x32_bf16(qf[0][dg], kf, s[0], 0, 0, 0);
            s[1] = __builtin_amdgcn_mfma_f32_16x16x32_bf16(qf[1][dg], kf, s[1], 0, 0, 0);
        }

        // ---- per-wave row max of this t-slice ----
        #pragma unroll
        for (int qs = 0; qs < 2; ++qs) {
            float rmax[4];
            #pragma unroll
            for (int r = 0; r < 4; ++r) rmax[r] = s[qs][r] * scale;
            #pragma unroll
            for (int off = 1; off < 16; off <<= 1)
                #pragma unroll
                for (int r = 0; r < 4; ++r)
                    rmax[r] = fmaxf(rmax[r], __shfl_xor(rmax[r], off));
            if (fr == 0)
                #pragma unroll
                for (int r = 0; r < 4; ++r)
                    wmax[qs * 16 + kg * 4 + r][w] = rmax[r];
        }
        __syncthreads();

        // ---- online update: P, per-wave sums ----
        float sc_my[4];
        #pragma unroll
        for (int qs = 0; qs < 2; ++qs) {
            float psum[4];
            #pragma unroll
            for (int r = 0; r < 4; ++r) {
                int row = qs * 16 + kg * 4 + r;
                float4 wm = *(const float4*)&wmax[row][0];
                float gm = fmaxf(fmaxf(wm.x, wm.y), fmaxf(wm.z, wm.w));
                float mnew = fmaxf(m[qs][r], gm);
                float scr = __expf(m[qs][r] - mnew);
                float p = __expf(s[qs][r] * scale - mnew);
                m[qs][r] = mnew;
                lsum[qs][r] *= scr;
                if (qs == myqs) sc_my[r] = scr;
                Ps[row][w * 16 + fr] = f2bf(p);
                psum[r] = p;
            }
            #pragma unroll
            for (int off = 1; off < 16; off <<= 1)
                #pragma unroll
                for (int r = 0; r < 4; ++r)
                    psum[r] += __shfl_xor(psum[r], off);
            if (fr == 0)
                #pragma unroll
                for (int r = 0; r < 4; ++r)
                    wsum[qs * 16 + kg * 4 + r][w] = psum[r];
        }
        __syncthreads();

        #pragma unroll
        for (int qs = 0; qs < 2; ++qs)
            #pragma unroll
            for (int r = 0; r < 4; ++r) {
                float4 wsv = *(const float4*)&wsum[qs * 16 + kg * 4 + r][0];
                lsum[qs][r] += wsv.x + wsv.y + wsv.z + wsv.w;
            }

        // ---- PV: O = O*sc + P(myqs) . V  (wave owns 3 d-subtiles) ----
        #pragma unroll
        for (int ds = 0; ds < 3; ++ds)
            #pragma unroll
            for (int r = 0; r < 4; ++r)
                acc_o[ds][r] *= sc_my[r];
        #pragma unroll
        for (int kk = 0; kk < 2; ++kk) {
            short8 pf = *(const short8*)&Ps[myqs * 16 + fr][kk * 32 + kg * 8];
            #pragma unroll
            for (int ds = 0; ds < 3; ++ds) {
                short8 vf = *(const short8*)&Vt[d0 + ds * 16 + fr][kk * 32 + kg * 8];
                acc_o[ds] = __builtin_amdgcn_mfma_f32_16x16x32_bf16(pf, vf, acc_o[ds], 0, 0, 0);
            }
        }
    }

    // ---- epilogue: normalize + store bf16 ----
    #pragma unroll
    for (int r = 0; r < 4; ++r) {
        float inv = 1.f / lsum[myqs][r];
        int q = row0 + myqs * 16 + kg * 4 + r;
        #pragma unroll
        for (int ds = 0; ds < 3; ++ds) {
            int d = h * 96 + d0 + ds * 16 + fr;
            ao[(size_t)q * C_S + d] = f2bf(acc_o[ds][r] * inv);
        }
    }
}

// ---------------------------------------------------------------------------
// fused token head + gather: out[a] = tf3[idx[a]] . co_w^T + co_b  (wave/atom)
__global__ __launch_bounds__(256) void k_atomout(
    const float* __restrict__ tf, const int* __restrict__ idx,
    const float* __restrict__ co_w, const float* __restrict__ co_b,
    float* __restrict__ out)
{
    int a = blockIdx.x * 4 + (threadIdx.x >> 6);
    int lane = threadIdx.x & 63;
    if (a >= N_ATOM) return;
    const float* base = tf + (size_t)idx[a] * C_S;
    float a0 = 0.f, a1 = 0.f, a2 = 0.f;
    #pragma unroll
    for (int i = 0; i < 6; ++i) {
        int c = lane + i * 64;
        float v = base[c];
        a0 += v * co_w[c];
        a1 += v * co_w[C_S + c];
        a2 += v * co_w[2 * C_S + c];
    }
    #pragma unroll
    for (int off = 32; off > 0; off >>= 1) {
        a0 += __shfl_down(a0, off);
        a1 += __shfl_down(a1, off);
        a2 += __shfl_down(a2, off);
    }
    if (lane == 0) {
        out[a * 3 + 0] = a0 + co_b[0];
        out[a * 3 + 1] = a1 + co_b[1];
        out[a * 3 + 2] = a2 + co_b[2];
    }
}

// ---------------------------------------------------------------------------
extern "C" void kernel_launch(void* const* d_in, const int* in_sizes, int n_in,
                              void* d_out, int out_size, void* d_ws, size_t ws_size,
                              hipStream_t stream)
{
    const float* x_noisy   = (const float*)d_in[0];
    const float* s         = (const float*)d_in[1];
    // d_in[2] = z : dead code in the reference (z_cond unused) -> never read
    const float* sigma     = (const float*)d_in[3];
    const int*   a2t       = (const int*)d_in[4];
    const float* fourier_w = (const float*)d_in[5];
    const float* fourier_b = (const float*)d_in[6];
    const float* ns_w      = (const float*)d_in[7];
    const float* ns_b      = (const float*)d_in[8];
    const float* lns_g     = (const float*)d_in[11];
    const float* lns_b     = (const float*)d_in[12];
    const float* ce_w      = (const float*)d_in[15];
    const float* ce_b      = (const float*)d_in[16];
    const float* in_w      = (const float*)d_in[17];
    const float* in_b      = (const float*)d_in[18];
    const float* out_w     = (const float*)d_in[19];
    const float* out_b     = (const float*)d_in[20];
    const float* ffln_g    = (const float*)d_in[21];
    const float* ffln_b    = (const float*)d_in[22];
    const float* ff1_w     = (const float*)d_in[23];
    const float* ff1_b     = (const float*)d_in[24];
    const float* ff2_w     = (const float*)d_in[25];
    const float* ff2_b     = (const float*)d_in[26];
    const float* co_w      = (const float*)d_in[27];
    const float* co_b      = (const float*)d_in[28];

    float* ws  = (float*)d_ws;
    float* out = (float*)d_out;
    __hip_bfloat16* qkvb  = (__hip_bfloat16*)(ws + OFF_QKV);
    __hip_bfloat16* tf1b  = (__hip_bfloat16*)(ws + OFF_TF1B);
    __hip_bfloat16* aob   = (__hip_bfloat16*)(ws + OFF_AOB);
    __hip_bfloat16* lnhb  = (__hip_bfloat16*)(ws + OFF_LNHB);
    __hip_bfloat16* h1b   = (__hip_bfloat16*)(ws + OFF_H1B);
    __hip_bfloat16* winb  = (__hip_bfloat16*)(ws + OFF_WINB);
    __hip_bfloat16* woutb = (__hip_bfloat16*)(ws + OFF_WOUTB);
    __hip_bfloat16* wf1b  = (__hip_bfloat16*)(ws + OFF_WF1B);
    __hip_bfloat16* wf2b  = (__hip_bfloat16*)(ws + OFF_WF2B);

    // weights -> bf16, zero segx, fourier/noise/nsproj setup
    hipLaunchKernelGGL(k_cvtw, dim3(865), dim3(256), 0, stream,
                       in_w, out_w, ff1_w, ff2_w, winb, woutb, wf1b, wf2b,
                       ws + OFF_SEGX, sigma, fourier_w, fourier_b, ns_w, ns_b,
                       ws + OFF_NSPROJ);
    hipLaunchKernelGGL(k_segsum, dim3(96), dim3(256), 0, stream,
                       x_noisy, a2t, ws + OFF_SEGX);
    hipLaunchKernelGGL(k_tokenfeat, dim3(N_TOK), dim3(128), 0, stream,
                       s, ws + OFF_SEGX, ws + OFF_NSPROJ, lns_g, lns_b,
                       ce_w, ce_b, ws + OFF_TF1, tf1b);
    // qkv = tf1 @ in_w^T + in_b  -> bf16 [1024,1152]
    hipLaunchKernelGGL((k_gemm<0, false, true>), dim3(18, 16), dim3(256), 0, stream,
                       tf1b, winb, in_b, nullptr, (float*)nullptr, qkvb,
                       1024, 1152, 384);
    // MFMA attention -> ao bf16
    hipLaunchKernelGGL(k_attn, dim3(N_TOK / QB, NH), dim3(256), 0, stream,
                       qkvb, aob);
    // tf2 = tf1 + ao @ out_w^T + out_b  (f32)
    hipLaunchKernelGGL((k_gemm<0, true, false>), dim3(6, 16), dim3(256), 0, stream,
                       aob, woutb, out_b, ws + OFF_TF1, ws + OFF_TF2,
                       (__hip_bfloat16*)nullptr, 1024, 384, 384);
    // lnh = LN(tf2) -> bf16
    hipLaunchKernelGGL(k_ln, dim3(N_TOK), dim3(128), 0, stream,
                       ws + OFF_TF2, ffln_g, ffln_b, lnhb);
    // h1 = silu(lnh @ ff1_w^T + ff1_b) -> bf16
    hipLaunchKernelGGL((k_gemm<1, false, true>), dim3(24, 16), dim3(256), 0, stream,
                       lnhb, wf1b, ff1_b, nullptr, (float*)nullptr, h1b,
                       1024, 1536, 384);
    // tf3 = tf2 + h1 @ ff2_w^T + ff2_b  (f32)
    hipLaunchKernelGGL((k_gemm<0, true, false>), dim3(6, 16), dim3(256), 0, stream,
                       h1b, wf2b, ff2_b, ws + OFF_TF2, ws + OFF_TF3,
                       (__hip_bfloat16*)nullptr, 1024, 384, 1536);
    // fused token head + gather
    hipLaunchKernelGGL(k_atomout, dim3(N_ATOM / 4, 1), dim3(256), 0, stream,
                       ws + OFF_TF3, a2t, co_w, co_b, out);
}